// Round 16
// baseline (867.874 us; speedup 1.0000x reference)
//
#include <hip/hip_runtime.h>
#include <cmath>

static constexpr float SCALE_ = 0.17677669529663687f; // 32^-0.5

typedef __attribute__((ext_vector_type(8))) _Float16 f16x8;
typedef __attribute__((ext_vector_type(8))) ushort u16x8;
typedef __attribute__((ext_vector_type(4))) float f32x4;

__device__ inline ushort f16u(float f) {
    union { _Float16 h; ushort u; } c;
    c.h = (_Float16)f;
    return c.u;
}

// async global->LDS, 16B per lane; LDS dest = wave-uniform base + lane*16
__device__ __forceinline__ void gld16(const ushort* g, ushort* l) {
    __builtin_amdgcn_global_load_lds(
        (const __attribute__((address_space(1))) unsigned int*)g,
        (__attribute__((address_space(3))) unsigned int*)l,
        16, 0, 0);
}

// ---------------------------------------------------------------------------
// Fused weight-combine: all 6 small GEMMs in one launch (job table).
// ---------------------------------------------------------------------------
struct SmallmmJobs {
    const float* Wa[6];
    const float* Wb[6];
    const float* sc[6];
    float*       out[6];
    int          NCb[6];
    int          base[7];
};
__global__ __launch_bounds__(256) void smallmm_all(SmallmmJobs J)
{
    int b = blockIdx.x;
    int j = 0;
    #pragma unroll
    for (int k = 1; k < 6; ++k) if (b >= J.base[k]) j = k;
    int idx = (b - J.base[j]) * 256 + threadIdx.x;
    int NCb = J.NCb[j];
    int n4  = NCb >> 2;
    int m   = idx / n4;
    int n0  = (idx - m * n4) << 2;
    if (m >= 192) return;
    const float* Wa = J.Wa[j];
    const float* Wb = J.Wb[j];
    float s = J.sc[j][0];
    float ax = 0.f, ay = 0.f, az = 0.f, aw = 0.f;
    for (int k = 0; k < 192; ++k) {
        float a = Wa[m * 192 + k];
        const float4 bv = *(const float4*)(Wb + (size_t)k * NCb + n0);
        ax += a * bv.x; ay += a * bv.y; az += a * bv.z; aw += a * bv.w;
    }
    float4 r = make_float4(ax * s, ay * s, az * s, aw * s);
    *(float4*)(J.out[j] + (size_t)m * NCb + n0) = r;
}

// ---------------------------------------------------------------------------
// Fused weight transpose+convert: all 11 weights in one launch.
// f32 [192][NC] -> K-slabbed transposed fp16 [6][NC][32]
// ---------------------------------------------------------------------------
struct WtJobs {
    const float* W[11];
    ushort*      dh[11];
    int          NC[11];
    int          base[12];
};
__global__ __launch_bounds__(256) void conv_wT_all(WtJobs J)
{
    int b = blockIdx.x;
    int j = 0;
    #pragma unroll
    for (int k = 1; k < 11; ++k) if (b >= J.base[k]) j = k;
    int idx = (b - J.base[j]) * 256 + threadIdx.x;
    int NC = J.NC[j];
    if (idx >= NC * 192) return;
    int n = idx / 192, k = idx - n * 192;
    float f = J.W[j][(long long)k * NC + n];
    long long o = ((long long)(k >> 5) * NC + n) * 32 + (k & 31);
    J.dh[j][o] = f16u(f);
}

// ---------------------------------------------------------------------------
// Activation f32 -> K-slabbed fp16 [6][Mc][32]; handles BOTH streams (t,r).
// ---------------------------------------------------------------------------
__global__ __launch_bounds__(256) void conv_x2(
    const float* __restrict__ src_t, const float* __restrict__ src_r,
    long long src_bs,
    ushort* __restrict__ dh_t, ushort* __restrict__ dh_r, int Mc)
{
    const long long SS = (long long)Mc * 32;
    const long long total8 = (long long)Mc * 24;
    for (long long t = (long long)blockIdx.x * 256 + threadIdx.x; t < 2 * total8;
         t += (long long)gridDim.x * 256) {
        const int second = (t >= total8);
        long long ti = second ? t - total8 : t;
        const float* src = second ? src_r : src_t;
        ushort* dh = second ? dh_r : dh_t;
        int m  = (int)(ti / 24);
        int c8 = (int)(ti - (long long)m * 24) * 8;
        int bb = m / 49, r = m - bb * 49;
        const float* sp = src + (long long)bb * src_bs + r * 192 + c8;
        float4 v0 = *(const float4*)sp;
        float4 v1 = *(const float4*)(sp + 4);
        float f[8] = {v0.x, v0.y, v0.z, v0.w, v1.x, v1.y, v1.z, v1.w};
        u16x8 h8;
        #pragma unroll
        for (int e = 0; e < 8; ++e) h8[e] = f16u(f[e]);
        long long o = (long long)(c8 >> 5) * SS + (long long)m * 32 + (c8 & 31);
        *(u16x8*)(dh + o) = h8;
    }
}

// ---------------------------------------------------------------------------
// fp16 MFMA GEMM: r13 tile (64Mx192N, 4 waves, wave 32x96) with a 3-buffer
// depth-2 counted-vmcnt pipeline (T4). Per 32-K slab q:
//   s_waitcnt vmcnt(4)   // own slab-q loads retired; slab q+1's in flight
//   s_barrier            // all waves' slab-q loads landed
//   stage(q+2 -> buf[(q+2)%3])  // that buffer's readers (slab q-1) passed
//   compute(q)           // 12 MFMAs, ds_reads from buf[q%3]
// One barrier per slab (same rate as r13); NO vmcnt(0) drain mid-loop.
// Chunked-bijective XCD swizzle; src chunk pre-swizzle c^=(row>>1)&3 with
// matching XOR on ds_read (r7-verified, 0 conflicts). Jobs a/b share B1.
// F32OUT: f32 scatter (b2=m/49); else slabbed fp16 out.
// A stage may overread past plane tail; launcher pads workspace 64KB.
// ---------------------------------------------------------------------------
template<int NC, bool DUAL, bool F32OUT>
__global__ __launch_bounds__(256, 3) void gemm_f16(
    const ushort* __restrict__ A1a, const ushort* __restrict__ A2a,
    const ushort* __restrict__ B2a, ushort* __restrict__ outHa,
    float* __restrict__ outFa,
    const ushort* __restrict__ A1b, const ushort* __restrict__ A2b,
    const ushort* __restrict__ B2b, ushort* __restrict__ outHb,
    float* __restrict__ outFb,
    const ushort* __restrict__ B1, const float* __restrict__ bias,
    long long out_bs, int M)
{
    __shared__ __align__(16) ushort AHs[3][2048];   // 64 x 32 per buffer
    __shared__ __align__(16) ushort BHs[3][6144];   // 192 x 32 per buffer

    constexpr int GX = NC / 192;
    // chunked bijective XCD swizzle (m204): XCD xc gets contiguous id range
    const int nwg = gridDim.x;
    const int orig = blockIdx.x;
    const int q8 = nwg >> 3, r8b = nwg & 7;
    const int xc = orig & 7, ix = orig >> 3;
    const int L = (xc < r8b ? xc * (q8 + 1) : r8b * (q8 + 1) + (xc - r8b) * q8) + ix;
    const int bm = L / (GX * 2);
    const int rem = L - bm * (GX * 2);
    const int bn = rem % GX;
    const int z  = rem / GX;

    const ushort* Ah1 = z ? A1b : A1a;
    const ushort* Ah2 = z ? A2b : A2a;
    const ushort* Bh2 = z ? B2b : B2a;

    const int tid = threadIdx.x;
    const int lane = tid & 63, wv = tid >> 6;
    const int wm = (wv >> 1) * 32;
    const int wn = (wv & 1) * 96;
    const int lr = lane & 15, lg = lane >> 4;
    const long long SS = (long long)M * 32;
    constexpr int NS = DUAL ? 12 : 6;

    const int at_row = tid >> 2;
    const int at_c   = (tid & 3) ^ ((tid >> 3) & 3);
    const long long a_src = (long long)(bm * 64 + at_row) * 32 + at_c * 8;
    int b_src[3];
    #pragma unroll
    for (int k = 0; k < 3; ++k) {
        int t = k * 256 + tid;
        int row = t >> 2, c = (t & 3) ^ ((t >> 3) & 3);
        b_src[k] = (bn * 192 + row) * 32 + c * 8;
    }
    const int wdst = wv * 512;

    int aoff[2], boff[6];
    #pragma unroll
    for (int i = 0; i < 2; ++i) {
        int row = wm + 16 * i + lr;
        aoff[i] = (row * 4 + (lg ^ ((row >> 1) & 3))) * 8;
    }
    #pragma unroll
    for (int j = 0; j < 6; ++j) {
        int row = wn + 16 * j + lr;
        boff[j] = (row * 4 + (lg ^ ((row >> 1) & 3))) * 8;
    }

    f32x4 acc[2][6] = {};

    auto stage = [&](int buf, int s) {
        const int k6 = (s < 6) ? s : s - 6;
        const ushort* AHp = (!DUAL || s < 6) ? Ah1 : Ah2;
        const ushort* BHp = (!DUAL || s < 6) ? B1  : Bh2;
        const long long asb = (long long)k6 * SS;
        const int bsb = k6 * (NC * 32);
        gld16(AHp + asb + a_src, AHs[buf] + wdst);        // 1 vmem/lane
        #pragma unroll
        for (int k = 0; k < 3; ++k)                       // 3 vmem/lane
            gld16(BHp + bsb + b_src[k], BHs[buf] + k * 2048 + wdst);
    };

    stage(0, 0);
    stage(1, 1);

    #pragma unroll
    for (int s = 0; s < NS; ++s) {
        const int cur = s % 3;
        if (s < NS - 1) { asm volatile("s_waitcnt vmcnt(4)" ::: "memory"); }
        else            { asm volatile("s_waitcnt vmcnt(0)" ::: "memory"); }
        __builtin_amdgcn_s_barrier();
        asm volatile("" ::: "memory");   // keep stage/ds_reads below barrier
        if (s + 2 < NS) stage((s + 2) % 3, s + 2);

        f16x8 ah[2];
        #pragma unroll
        for (int i = 0; i < 2; ++i)
            ah[i] = *(const f16x8*)&AHs[cur][aoff[i]];
        #pragma unroll
        for (int j = 0; j < 6; ++j) {
            f16x8 bh = *(const f16x8*)&BHs[cur][boff[j]];
            #pragma unroll
            for (int i = 0; i < 2; ++i)
                acc[i][j] = __builtin_amdgcn_mfma_f32_16x16x32_f16(ah[i], bh, acc[i][j], 0, 0, 0);
        }
        // all ds_reads are consumed by the MFMAs above (lgkm drained by use),
        // so waves reach the next barrier with buf[cur] fully read.
    }

    #pragma unroll
    for (int j = 0; j < 6; ++j) {
        const int c = bn * 192 + wn + 16 * j + lr;
        const float bv = bias ? bias[c] : 0.f;
        #pragma unroll
        for (int i = 0; i < 2; ++i)
            #pragma unroll
            for (int r = 0; r < 4; ++r) {
                int m = bm * 64 + wm + 16 * i + 4 * lg + r;
                if (m < M) {
                    float f = acc[i][j][r] + bv;
                    if constexpr (F32OUT) {
                        float* outF = z ? outFb : outFa;
                        int b2 = m / 49, r2 = m - b2 * 49;
                        outF[(long long)b2 * out_bs + r2 * 192 + c] = f;
                    } else {
                        ushort* outH = z ? outHb : outHa;
                        long long o = (long long)(c >> 5) * SS + (long long)m * 32 + (c & 31);
                        outH[o] = f16u(f);
                    }
                }
            }
    }
}

// ---------------------------------------------------------------------------
// MFMA differential attention on K-slabbed fp16 planes (r10-verified).
// ---------------------------------------------------------------------------
__global__ __launch_bounds__(256, 4) void attn_f16(
    const ushort* __restrict__ qT, const ushort* __restrict__ kT,
    const ushort* __restrict__ vT,
    const ushort* __restrict__ qR, const ushort* __restrict__ kR,
    const ushort* __restrict__ vR,
    long long SS,
    const float* __restrict__ rpb, const float* __restrict__ lam_ptr,
    ushort* __restrict__ otH, ushort* __restrict__ orH)
{
    __shared__ __align__(16) ushort Pth[64][72];
    __shared__ __align__(16) ushort Vs[2][32][70];  // [stream][d][j]
    __shared__ float bias_s[169];

    const int tid = threadIdx.x;
    const int bb = blockIdx.x / 6;
    const int h  = blockIdx.x - bb * 6;
    const int lane = tid & 63;
    const int w  = tid >> 6;
    const int li = lane & 15;
    const int lg = lane >> 4;
    const long long rowbase = (long long)bb * 49 * 32;
    const long long hb = (long long)h * SS + rowbase;

    for (int idx = tid; idx < 169; idx += 256) bias_s[idx] = rpb[idx * 6 + h];

    {
        const ushort* vsrc[2] = {vT + hb, vR + hb};
        for (int c = tid; c < 392; c += 256) {
            int s  = c / 196;
            int r2 = c - s * 196;
            int j  = r2 >> 2;
            int d4 = (r2 & 3) * 8;
            u16x8 v = *(const u16x8*)(vsrc[s] + j * 32 + d4);
            #pragma unroll
            for (int e = 0; e < 8; ++e) Vs[s][d4 + e][j] = v[e];
        }
        for (int c = tid; c < 2 * 32 * 21; c += 256) {
            int s  = c / (32 * 21);
            int r1 = c - s * (32 * 21);
            int d  = r1 / 21;
            int j  = 49 + (r1 - d * 21);
            Vs[s][d][j] = 0;
        }
    }

    float lraw = lam_ptr[0];
    float lam = 1.f / (1.f + __expf(-lraw));
    lam = fminf(fmaxf(lam, 0.01f), 0.99f);

    const int irow = min(w * 16 + li, 48);

    f32x4 st[2][4];
    #pragma unroll
    for (int s = 0; s < 2; ++s) {
        const ushort* qb = (s ? qR : qT) + hb;
        const ushort* kb = (s ? kR : kT) + hb;
        f16x8 qh = *(const f16x8*)(qb + irow * 32 + 8 * lg);
        #pragma unroll
        for (int jt = 0; jt < 4; ++jt) {
            int jr = jt * 16 + li; if (jr > 48) jr = 48;
            f16x8 kh = *(const f16x8*)(kb + jr * 32 + 8 * lg);
            f32x4 c = {};
            c = __builtin_amdgcn_mfma_f32_16x16x32_f16(kh, qh, c, 0, 0, 0);
            st[s][jt] = c;
        }
    }
    __syncthreads();   // bias_s + Vs staged (only barrier)

    const int ri = (irow * 9363) >> 16;
    const int ci = irow - 7 * ri;
    float bias_v[4][4];
    #pragma unroll
    for (int jt = 0; jt < 4; ++jt)
        #pragma unroll
        for (int r = 0; r < 4; ++r) {
            int j = jt * 16 + 4 * lg + r;
            int jc = (j < 49) ? j : 48;
            int rj = (jc * 9363) >> 16;
            int cj = jc - 7 * rj;
            bias_v[jt][r] = bias_s[(ri - rj + 6) * 13 + (ci - cj + 6)];
        }

    float p[2][4][4];
    #pragma unroll
    for (int s = 0; s < 2; ++s) {
        float m = -1e30f;
        #pragma unroll
        for (int jt = 0; jt < 4; ++jt)
            #pragma unroll
            for (int r = 0; r < 4; ++r) {
                int j = jt * 16 + 4 * lg + r;
                float sv = (j < 49) ? (st[s][jt][r] * SCALE_ + bias_v[jt][r]) : -1e30f;
                p[s][jt][r] = sv;
                m = fmaxf(m, sv);
            }
        m = fmaxf(m, __shfl_xor(m, 16));
        m = fmaxf(m, __shfl_xor(m, 32));
        float sum = 0.f;
        #pragma unroll
        for (int jt = 0; jt < 4; ++jt)
            #pragma unroll
            for (int r = 0; r < 4; ++r) {
                float e = __expf(p[s][jt][r] - m);
                p[s][jt][r] = e;
                sum += e;
            }
        sum += __shfl_xor(sum, 16);
        sum += __shfl_xor(sum, 32);
        float inv = 1.f / sum;
        #pragma unroll
        for (int jt = 0; jt < 4; ++jt)
            #pragma unroll
            for (int r = 0; r < 4; ++r)
                p[s][jt][r] *= inv;
    }

    const int prow = w * 16 + li;
    #pragma unroll
    for (int s = 0; s < 2; ++s) {
        #pragma unroll
        for (int jt = 0; jt < 4; ++jt) {
            ushort4 h4;
            #pragma unroll
            for (int r = 0; r < 4; ++r) {
                float at = p[0][jt][r], ar = p[1][jt][r];
                float f = (s == 0) ? (at - lam * ar) : (ar - lam * at);
                ((ushort*)&h4)[r] = f16u(f);
            }
            *(ushort4*)&Pth[prow][jt * 16 + 4 * lg] = h4;
        }

        f32x4 acc[2] = {};
        #pragma unroll
        for (int ks = 0; ks < 2; ++ks) {
            f16x8 pa = *(const f16x8*)&Pth[prow][ks * 32 + 8 * lg];
            #pragma unroll
            for (int dt = 0; dt < 2; ++dt) {
                f16x8 vh = *(const f16x8*)&Vs[s][dt * 16 + li][ks * 32 + 8 * lg];
                acc[dt] = __builtin_amdgcn_mfma_f32_16x16x32_f16(pa, vh, acc[dt], 0, 0, 0);
            }
        }
        ushort* oph = s ? orH : otH;
        #pragma unroll
        for (int dt = 0; dt < 2; ++dt)
            #pragma unroll
            for (int r = 0; r < 4; ++r) {
                int i = w * 16 + 4 * lg + r;
                if (i < 49) {
                    long long o = (long long)h * SS + rowbase + (long long)i * 32 + dt * 16 + li;
                    oph[o] = f16u(acc[dt][r]);
                }
            }
    }
}

// ---------------------------------------------------------------------------
extern "C" void kernel_launch(void* const* d_in, const int* in_sizes, int n_in,
                              void* d_out, int out_size, void* d_ws, size_t ws_size,
                              hipStream_t stream)
{
    const float* x_sa      = (const float*)d_in[0];
    const float* x_ca      = (const float*)d_in[1];
    const float* lam_sa    = (const float*)d_in[2];
    const float* lam_ca    = (const float*)d_in[3];
    const float* sa_enh    = (const float*)d_in[4];
    const float* ca_enh    = (const float*)d_in[5];
    const float* W_sa_qkv  = (const float*)d_in[6];
    const float* b_sa_qkv  = (const float*)d_in[7];
    const float* W_sa_ct   = (const float*)d_in[8];
    const float* W_sa_cr   = (const float*)d_in[9];
    const float* W_ca_q    = (const float*)d_in[10];
    const float* b_ca_q    = (const float*)d_in[11];
    const float* W_ca_kv   = (const float*)d_in[12];
    const float* b_ca_kv   = (const float*)d_in[13];
    const float* W_ca_ct   = (const float*)d_in[14];
    const float* W_ca_cr   = (const float*)d_in[15];
    const float* rpb       = (const float*)d_in[16];
    const float* W_proj_sa = (const float*)d_in[17];
    const float* b_proj_sa = (const float*)d_in[18];
    const float* W_proj_ca = (const float*)d_in[19];
    const float* b_proj_ca = (const float*)d_in[20];
    float* out = (float*)d_out;
    float* ws  = (float*)d_ws;

    // ---- f32 combined-weight temps ----
    float* CW0 = ws;             // 192x576
    float* CW1 = CW0 + 110592;
    float* CW2 = CW1 + 110592;   // 192x192
    float* CW3 = CW2 + 36864;
    float* CW4 = CW3 + 36864;    // 192x384
    float* CW5 = CW4 + 73728;

    {
        SmallmmJobs J;
        J.Wa[0]=W_sa_cr; J.Wb[0]=W_sa_qkv; J.sc[0]=sa_enh; J.out[0]=CW0; J.NCb[0]=576;
        J.Wa[1]=W_sa_ct; J.Wb[1]=W_sa_qkv; J.sc[1]=sa_enh; J.out[1]=CW1; J.NCb[1]=576;
        J.Wa[2]=W_ca_cr; J.Wb[2]=W_ca_q;   J.sc[2]=ca_enh; J.out[2]=CW2; J.NCb[2]=192;
        J.Wa[3]=W_ca_ct; J.Wb[3]=W_ca_q;   J.sc[3]=ca_enh; J.out[3]=CW3; J.NCb[3]=192;
        J.Wa[4]=W_ca_cr; J.Wb[4]=W_ca_kv;  J.sc[4]=ca_enh; J.out[4]=CW4; J.NCb[4]=384;
        J.Wa[5]=W_ca_ct; J.Wb[5]=W_ca_kv;  J.sc[5]=ca_enh; J.out[5]=CW5; J.NCb[5]=384;
        int bs[7] = {0,108,216,252,288,360,432};
        for (int i = 0; i < 7; ++i) J.base[i] = bs[i];
        smallmm_all<<<432, 256, 0, stream>>>(J);
    }

    // ---- K-slabbed fp16 weights ----
    ushort* wb = (ushort*)(ws + 442368);
    ushort* WsaqH = wb;
    ushort* C0H  = WsaqH + 110592;
    ushort* C1H  = C0H + 110592;
    ushort* WcqH = C1H + 110592;
    ushort* C2H  = WcqH + 36864;
    ushort* C3H  = C2H + 36864;
    ushort* WckH = C3H + 36864;
    ushort* C4H  = WckH + 73728;
    ushort* C5H  = C4H + 73728;
    ushort* WpsH = C5H + 73728;
    ushort* WpcH = WpsH + 36864;
    ushort* chunkU = WpcH + 36864;       // = wb + 737280

    {
        WtJobs J;
        const float* Ws[11] = {W_sa_qkv, CW0, CW1, W_ca_q, CW2, CW3,
                               W_ca_kv, CW4, CW5, W_proj_sa, W_proj_ca};
        ushort* Ds[11] = {WsaqH, C0H, C1H, WcqH, C2H, C3H,
                          WckH, C4H, C5H, WpsH, WpcH};
        int NCs[11] = {576,576,576,192,192,192,384,384,384,192,192};
        int bs[12] = {0,432,864,1296,1440,1584,1728,2016,2304,2592,2736,2880};
        for (int i = 0; i < 11; ++i) { J.W[i]=Ws[i]; J.dh[i]=Ds[i]; J.NC[i]=NCs[i]; }
        for (int i = 0; i < 12; ++i) J.base[i] = bs[i];
        conv_wT_all<<<2880, 256, 0, stream>>>(J);
    }

    // ---- chunking: 188160 bytes per batch element, 64KB tail pad.
    //      Cap at 1024 so per-chunk intermediates (~192MB) fit the 256MB L3. ----
    long long avail = (long long)ws_size - 442368LL * 4 - 737280LL * 2 - 65536;
    int cbmax = (int)(avail / 188160);
    if (cbmax > 1024) cbmax = 1024;
    if (cbmax < 1) cbmax = 1;

    const long long OUT1 = 2LL * 2048 * 49 * 192;
    dim3 blk(256);

    for (int c0 = 0; c0 < 2048; c0 += cbmax) {
        int cb = (c0 + cbmax <= 2048) ? cbmax : (2048 - c0);
        int M = cb * 49;
        long long SS = (long long)M * 32;
        int gy = (M + 63) / 64;
        int cblk = (int)(((long long)M * 48 + 255) / 256);
        if (cblk > 4096) cblk = 4096;

        // 1-D grids for the swizzled GEMM: nwg = GX * gy * 2
        dim3 g1(6 * gy), g2(2 * gy), g3(4 * gy);

        // =========================== SA branch ===========================
        ushort* XtH = chunkU;                              // [6][M][32]
        ushort* XrH = XtH + (long long)cbmax * 9408;
        ushort* QtH = XrH + (long long)cbmax * 9408;       // [18][M][32]
        ushort* QrH = QtH + (long long)cbmax * 28224;
        ushort* OtH = QrH + (long long)cbmax * 28224;      // [6][M][32]
        ushort* OrH = OtH + (long long)cbmax * 9408;

        conv_x2<<<cblk, blk, 0, stream>>>(
            x_sa + (long long)c0 * 9408, x_sa + (2048LL + c0) * 9408, 9408,
            XtH, XrH, M);

        gemm_f16<576, true, false><<<g1, blk, 0, stream>>>(
            XtH, XrH, C0H, QtH, nullptr,
            XrH, XtH, C1H, QrH, nullptr,
            WsaqH, b_sa_qkv, 0, M);

        attn_f16<<<cb * 6, blk, 0, stream>>>(
            QtH, QtH + 6 * SS, QtH + 12 * SS,
            QrH, QrH + 6 * SS, QrH + 12 * SS,
            SS, rpb, lam_sa, OtH, OrH);

        gemm_f16<192, false, true><<<g2, blk, 0, stream>>>(
            OtH, nullptr, nullptr, nullptr, out + (long long)c0 * 9408,
            OrH, nullptr, nullptr, nullptr, out + (2048LL + c0) * 9408,
            WpsH, b_proj_sa, 9408, M);

        // =========================== CA branch ===========================
        ushort* CXtH = chunkU;                             // [6][M][32]
        ushort* CXrH = CXtH + (long long)cbmax * 9408;
        ushort* CQtH = CXrH + (long long)cbmax * 9408;     // [6][M][32]
        ushort* CQrH = CQtH + (long long)cbmax * 9408;
        ushort* KtH  = CQrH + (long long)cbmax * 9408;     // [12][M][32]
        ushort* KrH  = KtH + (long long)cbmax * 18816;
        ushort* COtH = KrH + (long long)cbmax * 18816;     // [6][M][32]
        ushort* COrH = COtH + (long long)cbmax * 9408;

        conv_x2<<<cblk, blk, 0, stream>>>(
            x_ca + (long long)c0 * 18816, x_ca + (long long)c0 * 18816 + 9408, 18816,
            CXtH, CXrH, M);

        gemm_f16<192, true, false><<<g2, blk, 0, stream>>>(
            CXtH, CXrH, C2H, CQtH, nullptr,
            CXrH, CXtH, C3H, CQrH, nullptr,
            WcqH, b_ca_q, 0, M);

        gemm_f16<384, true, false><<<g3, blk, 0, stream>>>(
            CXtH, CXrH, C4H, KtH, nullptr,
            CXrH, CXtH, C5H, KrH, nullptr,
            WckH, b_ca_kv, 0, M);

        attn_f16<<<cb * 6, blk, 0, stream>>>(
            CQtH, KtH, KtH + 6 * SS,
            CQrH, KrH, KrH + 6 * SS,
            SS, rpb, lam_ca, COtH, COrH);

        gemm_f16<192, false, true><<<g2, blk, 0, stream>>>(
            COtH, nullptr, nullptr, nullptr, out + OUT1 + (long long)c0 * 18816,
            COrH, nullptr, nullptr, nullptr, out + OUT1 + (long long)c0 * 18816 + 9408,
            WpcH, b_proj_ca, 18816, M);
    }
}

// Round 17
// 792.854 us; speedup vs baseline: 1.0946x; 1.0946x over previous
//
#include <hip/hip_runtime.h>
#include <cmath>

static constexpr float SCALE_ = 0.17677669529663687f; // 32^-0.5

typedef __attribute__((ext_vector_type(8))) _Float16 f16x8;
typedef __attribute__((ext_vector_type(8))) ushort u16x8;
typedef __attribute__((ext_vector_type(4))) float f32x4;

__device__ inline ushort f16u(float f) {
    union { _Float16 h; ushort u; } c;
    c.h = (_Float16)f;
    return c.u;
}

// async global->LDS, 16B per lane; LDS dest = wave-uniform base + lane*16
__device__ __forceinline__ void gld16(const ushort* g, ushort* l) {
    __builtin_amdgcn_global_load_lds(
        (const __attribute__((address_space(1))) unsigned int*)g,
        (__attribute__((address_space(3))) unsigned int*)l,
        16, 0, 0);
}

// ---------------------------------------------------------------------------
// Fused weight-combine: all 6 small GEMMs in one launch (job table).
// ---------------------------------------------------------------------------
struct SmallmmJobs {
    const float* Wa[6];
    const float* Wb[6];
    const float* sc[6];
    float*       out[6];
    int          NCb[6];
    int          base[7];
};
__global__ __launch_bounds__(256) void smallmm_all(SmallmmJobs J)
{
    int b = blockIdx.x;
    int j = 0;
    #pragma unroll
    for (int k = 1; k < 6; ++k) if (b >= J.base[k]) j = k;
    int idx = (b - J.base[j]) * 256 + threadIdx.x;
    int NCb = J.NCb[j];
    int n4  = NCb >> 2;
    int m   = idx / n4;
    int n0  = (idx - m * n4) << 2;
    if (m >= 192) return;
    const float* Wa = J.Wa[j];
    const float* Wb = J.Wb[j];
    float s = J.sc[j][0];
    float ax = 0.f, ay = 0.f, az = 0.f, aw = 0.f;
    for (int k = 0; k < 192; ++k) {
        float a = Wa[m * 192 + k];
        const float4 bv = *(const float4*)(Wb + (size_t)k * NCb + n0);
        ax += a * bv.x; ay += a * bv.y; az += a * bv.z; aw += a * bv.w;
    }
    float4 r = make_float4(ax * s, ay * s, az * s, aw * s);
    *(float4*)(J.out[j] + (size_t)m * NCb + n0) = r;
}

// ---------------------------------------------------------------------------
// Fused weight transpose+convert: all 11 weights in one launch.
// f32 [192][NC] -> K-slabbed transposed fp16 [6][NC][32]
// ---------------------------------------------------------------------------
struct WtJobs {
    const float* W[11];
    ushort*      dh[11];
    int          NC[11];
    int          base[12];
};
__global__ __launch_bounds__(256) void conv_wT_all(WtJobs J)
{
    int b = blockIdx.x;
    int j = 0;
    #pragma unroll
    for (int k = 1; k < 11; ++k) if (b >= J.base[k]) j = k;
    int idx = (b - J.base[j]) * 256 + threadIdx.x;
    int NC = J.NC[j];
    if (idx >= NC * 192) return;
    int n = idx / 192, k = idx - n * 192;
    float f = J.W[j][(long long)k * NC + n];
    long long o = ((long long)(k >> 5) * NC + n) * 32 + (k & 31);
    J.dh[j][o] = f16u(f);
}

// ---------------------------------------------------------------------------
// Activation f32 -> K-slabbed fp16 [6][Mc][32]; handles BOTH streams (t,r).
// ---------------------------------------------------------------------------
__global__ __launch_bounds__(256) void conv_x2(
    const float* __restrict__ src_t, const float* __restrict__ src_r,
    long long src_bs,
    ushort* __restrict__ dh_t, ushort* __restrict__ dh_r, int Mc)
{
    const long long SS = (long long)Mc * 32;
    const long long total8 = (long long)Mc * 24;
    for (long long t = (long long)blockIdx.x * 256 + threadIdx.x; t < 2 * total8;
         t += (long long)gridDim.x * 256) {
        const int second = (t >= total8);
        long long ti = second ? t - total8 : t;
        const float* src = second ? src_r : src_t;
        ushort* dh = second ? dh_r : dh_t;
        int m  = (int)(ti / 24);
        int c8 = (int)(ti - (long long)m * 24) * 8;
        int bb = m / 49, r = m - bb * 49;
        const float* sp = src + (long long)bb * src_bs + r * 192 + c8;
        float4 v0 = *(const float4*)sp;
        float4 v1 = *(const float4*)(sp + 4);
        float f[8] = {v0.x, v0.y, v0.z, v0.w, v1.x, v1.y, v1.z, v1.w};
        u16x8 h8;
        #pragma unroll
        for (int e = 0; e < 8; ++e) h8[e] = f16u(f[e]);
        long long o = (long long)(c8 >> 5) * SS + (long long)m * 32 + (c8 & 31);
        *(u16x8*)(dh + o) = h8;
    }
}

// ---------------------------------------------------------------------------
// fp16 MFMA GEMM: r13-verified optimum (772us config). 64Mx192N block, BK=64
// phases (two 32-K slabs per barrier pair), chunked-bijective XCD swizzle.
// Per phase: stage A(64x64)+B(192x64) via global_load_lds w16 (linear dest,
// src chunk c ^= (row>>1)&3, same XOR on ds_read -> 0 conflicts) then
// 24 MFMAs/wave. 4 waves (2m x 2n), wave 32x96. LDS 32KB, 4 blocks/CU.
// Jobs a/b share B1 (z selects). F32OUT: f32 scatter; else slabbed fp16.
// A stage may overread past plane tail; launcher pads workspace 64KB.
// ---------------------------------------------------------------------------
template<int NC, bool DUAL, bool F32OUT>
__global__ __launch_bounds__(256, 4) void gemm_f16(
    const ushort* __restrict__ A1a, const ushort* __restrict__ A2a,
    const ushort* __restrict__ B2a, ushort* __restrict__ outHa,
    float* __restrict__ outFa,
    const ushort* __restrict__ A1b, const ushort* __restrict__ A2b,
    const ushort* __restrict__ B2b, ushort* __restrict__ outHb,
    float* __restrict__ outFb,
    const ushort* __restrict__ B1, const float* __restrict__ bias,
    long long out_bs, int M)
{
    __shared__ __align__(16) ushort AHs[2][2048];   // 2 slabs x 64 x 32
    __shared__ __align__(16) ushort BHs[2][6144];   // 2 slabs x 192 x 32

    constexpr int GX = NC / 192;
    // chunked bijective XCD swizzle (m204): XCD xc gets contiguous id range
    const int nwg = gridDim.x;
    const int orig = blockIdx.x;
    const int q8 = nwg >> 3, r8b = nwg & 7;
    const int xc = orig & 7, ix = orig >> 3;
    const int L = (xc < r8b ? xc * (q8 + 1) : r8b * (q8 + 1) + (xc - r8b) * q8) + ix;
    const int bm = L / (GX * 2);
    const int rem = L - bm * (GX * 2);
    const int bn = rem % GX;
    const int z  = rem / GX;

    const ushort* Ah1 = z ? A1b : A1a;
    const ushort* Ah2 = z ? A2b : A2a;
    const ushort* Bh2 = z ? B2b : B2a;

    const int tid = threadIdx.x;
    const int lane = tid & 63, wv = tid >> 6;
    const int wm = (wv >> 1) * 32;
    const int wn = (wv & 1) * 96;
    const int lr = lane & 15, lg = lane >> 4;
    const long long SS = (long long)M * 32;
    constexpr int NP = DUAL ? 6 : 3;   // phases of 2 slabs

    const int at_row = tid >> 2;
    const int at_c   = (tid & 3) ^ ((tid >> 3) & 3);
    const long long a_src = (long long)(bm * 64 + at_row) * 32 + at_c * 8;
    int b_src[3];
    #pragma unroll
    for (int k = 0; k < 3; ++k) {
        int t = k * 256 + tid;
        int row = t >> 2, c = (t & 3) ^ ((t >> 3) & 3);
        b_src[k] = (bn * 192 + row) * 32 + c * 8;
    }
    const int wdst = wv * 512;

    int aoff[2], boff[6];
    #pragma unroll
    for (int i = 0; i < 2; ++i) {
        int row = wm + 16 * i + lr;
        aoff[i] = (row * 4 + (lg ^ ((row >> 1) & 3))) * 8;
    }
    #pragma unroll
    for (int j = 0; j < 6; ++j) {
        int row = wn + 16 * j + lr;
        boff[j] = (row * 4 + (lg ^ ((row >> 1) & 3))) * 8;
    }

    f32x4 acc[2][6] = {};

    #pragma unroll
    for (int p = 0; p < NP; ++p) {
        // stage two slabs into the two LDS halves
        #pragma unroll
        for (int hbf = 0; hbf < 2; ++hbf) {
            const int s = 2 * p + hbf;
            const int k6 = (s < 6) ? s : s - 6;
            const ushort* AHp = (!DUAL || s < 6) ? Ah1 : Ah2;
            const ushort* BHp = (!DUAL || s < 6) ? B1  : Bh2;
            const long long asb = (long long)k6 * SS;
            const int bsb = k6 * (NC * 32);
            gld16(AHp + asb + a_src, AHs[hbf] + wdst);
            #pragma unroll
            for (int k = 0; k < 3; ++k)
                gld16(BHp + bsb + b_src[k], BHs[hbf] + k * 2048 + wdst);
        }
        __syncthreads();   // drain vmcnt -> both slabs visible

        #pragma unroll
        for (int hbf = 0; hbf < 2; ++hbf) {
            f16x8 ah[2];
            #pragma unroll
            for (int i = 0; i < 2; ++i)
                ah[i] = *(const f16x8*)&AHs[hbf][aoff[i]];
            #pragma unroll
            for (int j = 0; j < 6; ++j) {
                f16x8 bh = *(const f16x8*)&BHs[hbf][boff[j]];
                #pragma unroll
                for (int i = 0; i < 2; ++i)
                    acc[i][j] = __builtin_amdgcn_mfma_f32_16x16x32_f16(ah[i], bh, acc[i][j], 0, 0, 0);
            }
        }
        __syncthreads();   // all reads done before next stage overwrites
    }

    #pragma unroll
    for (int j = 0; j < 6; ++j) {
        const int c = bn * 192 + wn + 16 * j + lr;
        const float bv = bias ? bias[c] : 0.f;
        #pragma unroll
        for (int i = 0; i < 2; ++i)
            #pragma unroll
            for (int r = 0; r < 4; ++r) {
                int m = bm * 64 + wm + 16 * i + 4 * lg + r;
                if (m < M) {
                    float f = acc[i][j][r] + bv;
                    if constexpr (F32OUT) {
                        float* outF = z ? outFb : outFa;
                        int b2 = m / 49, r2 = m - b2 * 49;
                        outF[(long long)b2 * out_bs + r2 * 192 + c] = f;
                    } else {
                        ushort* outH = z ? outHb : outHa;
                        long long o = (long long)(c >> 5) * SS + (long long)m * 32 + (c & 31);
                        outH[o] = f16u(f);
                    }
                }
            }
    }
}

// ---------------------------------------------------------------------------
// MFMA differential attention on K-slabbed fp16 planes (r10-verified),
// + T5 s_setprio around MFMA clusters (m191: +4-7% on attn-style kernels).
// ---------------------------------------------------------------------------
__global__ __launch_bounds__(256, 4) void attn_f16(
    const ushort* __restrict__ qT, const ushort* __restrict__ kT,
    const ushort* __restrict__ vT,
    const ushort* __restrict__ qR, const ushort* __restrict__ kR,
    const ushort* __restrict__ vR,
    long long SS,
    const float* __restrict__ rpb, const float* __restrict__ lam_ptr,
    ushort* __restrict__ otH, ushort* __restrict__ orH)
{
    __shared__ __align__(16) ushort Pth[64][72];
    __shared__ __align__(16) ushort Vs[2][32][70];  // [stream][d][j]
    __shared__ float bias_s[169];

    const int tid = threadIdx.x;
    const int bb = blockIdx.x / 6;
    const int h  = blockIdx.x - bb * 6;
    const int lane = tid & 63;
    const int w  = tid >> 6;
    const int li = lane & 15;
    const int lg = lane >> 4;
    const long long rowbase = (long long)bb * 49 * 32;
    const long long hb = (long long)h * SS + rowbase;

    for (int idx = tid; idx < 169; idx += 256) bias_s[idx] = rpb[idx * 6 + h];

    {
        const ushort* vsrc[2] = {vT + hb, vR + hb};
        for (int c = tid; c < 392; c += 256) {
            int s  = c / 196;
            int r2 = c - s * 196;
            int j  = r2 >> 2;
            int d4 = (r2 & 3) * 8;
            u16x8 v = *(const u16x8*)(vsrc[s] + j * 32 + d4);
            #pragma unroll
            for (int e = 0; e < 8; ++e) Vs[s][d4 + e][j] = v[e];
        }
        for (int c = tid; c < 2 * 32 * 21; c += 256) {
            int s  = c / (32 * 21);
            int r1 = c - s * (32 * 21);
            int d  = r1 / 21;
            int j  = 49 + (r1 - d * 21);
            Vs[s][d][j] = 0;
        }
    }

    float lraw = lam_ptr[0];
    float lam = 1.f / (1.f + __expf(-lraw));
    lam = fminf(fmaxf(lam, 0.01f), 0.99f);

    const int irow = min(w * 16 + li, 48);

    f32x4 st[2][4];
    __builtin_amdgcn_s_setprio(1);
    #pragma unroll
    for (int s = 0; s < 2; ++s) {
        const ushort* qb = (s ? qR : qT) + hb;
        const ushort* kb = (s ? kR : kT) + hb;
        f16x8 qh = *(const f16x8*)(qb + irow * 32 + 8 * lg);
        #pragma unroll
        for (int jt = 0; jt < 4; ++jt) {
            int jr = jt * 16 + li; if (jr > 48) jr = 48;
            f16x8 kh = *(const f16x8*)(kb + jr * 32 + 8 * lg);
            f32x4 c = {};
            c = __builtin_amdgcn_mfma_f32_16x16x32_f16(kh, qh, c, 0, 0, 0);
            st[s][jt] = c;
        }
    }
    __builtin_amdgcn_s_setprio(0);
    __syncthreads();   // bias_s + Vs staged (only barrier)

    const int ri = (irow * 9363) >> 16;
    const int ci = irow - 7 * ri;
    float bias_v[4][4];
    #pragma unroll
    for (int jt = 0; jt < 4; ++jt)
        #pragma unroll
        for (int r = 0; r < 4; ++r) {
            int j = jt * 16 + 4 * lg + r;
            int jc = (j < 49) ? j : 48;
            int rj = (jc * 9363) >> 16;
            int cj = jc - 7 * rj;
            bias_v[jt][r] = bias_s[(ri - rj + 6) * 13 + (ci - cj + 6)];
        }

    float p[2][4][4];
    #pragma unroll
    for (int s = 0; s < 2; ++s) {
        float m = -1e30f;
        #pragma unroll
        for (int jt = 0; jt < 4; ++jt)
            #pragma unroll
            for (int r = 0; r < 4; ++r) {
                int j = jt * 16 + 4 * lg + r;
                float sv = (j < 49) ? (st[s][jt][r] * SCALE_ + bias_v[jt][r]) : -1e30f;
                p[s][jt][r] = sv;
                m = fmaxf(m, sv);
            }
        m = fmaxf(m, __shfl_xor(m, 16));
        m = fmaxf(m, __shfl_xor(m, 32));
        float sum = 0.f;
        #pragma unroll
        for (int jt = 0; jt < 4; ++jt)
            #pragma unroll
            for (int r = 0; r < 4; ++r) {
                float e = __expf(p[s][jt][r] - m);
                p[s][jt][r] = e;
                sum += e;
            }
        sum += __shfl_xor(sum, 16);
        sum += __shfl_xor(sum, 32);
        float inv = 1.f / sum;
        #pragma unroll
        for (int jt = 0; jt < 4; ++jt)
            #pragma unroll
            for (int r = 0; r < 4; ++r)
                p[s][jt][r] *= inv;
    }

    const int prow = w * 16 + li;
    #pragma unroll
    for (int s = 0; s < 2; ++s) {
        #pragma unroll
        for (int jt = 0; jt < 4; ++jt) {
            ushort4 h4;
            #pragma unroll
            for (int r = 0; r < 4; ++r) {
                float at = p[0][jt][r], ar = p[1][jt][r];
                float f = (s == 0) ? (at - lam * ar) : (ar - lam * at);
                ((ushort*)&h4)[r] = f16u(f);
            }
            *(ushort4*)&Pth[prow][jt * 16 + 4 * lg] = h4;
        }

        f32x4 acc[2] = {};
        __builtin_amdgcn_s_setprio(1);
        #pragma unroll
        for (int ks = 0; ks < 2; ++ks) {
            f16x8 pa = *(const f16x8*)&Pth[prow][ks * 32 + 8 * lg];
            #pragma unroll
            for (int dt = 0; dt < 2; ++dt) {
                f16x8 vh = *(const f16x8*)&Vs[s][dt * 16 + li][ks * 32 + 8 * lg];
                acc[dt] = __builtin_amdgcn_mfma_f32_16x16x32_f16(pa, vh, acc[dt], 0, 0, 0);
            }
        }
        __builtin_amdgcn_s_setprio(0);
        ushort* oph = s ? orH : otH;
        #pragma unroll
        for (int dt = 0; dt < 2; ++dt)
            #pragma unroll
            for (int r = 0; r < 4; ++r) {
                int i = w * 16 + 4 * lg + r;
                if (i < 49) {
                    long long o = (long long)h * SS + rowbase + (long long)i * 32 + dt * 16 + li;
                    oph[o] = f16u(acc[dt][r]);
                }
            }
    }
}

// ---------------------------------------------------------------------------
extern "C" void kernel_launch(void* const* d_in, const int* in_sizes, int n_in,
                              void* d_out, int out_size, void* d_ws, size_t ws_size,
                              hipStream_t stream)
{
    const float* x_sa      = (const float*)d_in[0];
    const float* x_ca      = (const float*)d_in[1];
    const float* lam_sa    = (const float*)d_in[2];
    const float* lam_ca    = (const float*)d_in[3];
    const float* sa_enh    = (const float*)d_in[4];
    const float* ca_enh    = (const float*)d_in[5];
    const float* W_sa_qkv  = (const float*)d_in[6];
    const float* b_sa_qkv  = (const float*)d_in[7];
    const float* W_sa_ct   = (const float*)d_in[8];
    const float* W_sa_cr   = (const float*)d_in[9];
    const float* W_ca_q    = (const float*)d_in[10];
    const float* b_ca_q    = (const float*)d_in[11];
    const float* W_ca_kv   = (const float*)d_in[12];
    const float* b_ca_kv   = (const float*)d_in[13];
    const float* W_ca_ct   = (const float*)d_in[14];
    const float* W_ca_cr   = (const float*)d_in[15];
    const float* rpb       = (const float*)d_in[16];
    const float* W_proj_sa = (const float*)d_in[17];
    const float* b_proj_sa = (const float*)d_in[18];
    const float* W_proj_ca = (const float*)d_in[19];
    const float* b_proj_ca = (const float*)d_in[20];
    float* out = (float*)d_out;
    float* ws  = (float*)d_ws;

    // ---- f32 combined-weight temps ----
    float* CW0 = ws;             // 192x576
    float* CW1 = CW0 + 110592;
    float* CW2 = CW1 + 110592;   // 192x192
    float* CW3 = CW2 + 36864;
    float* CW4 = CW3 + 36864;    // 192x384
    float* CW5 = CW4 + 73728;

    {
        SmallmmJobs J;
        J.Wa[0]=W_sa_cr; J.Wb[0]=W_sa_qkv; J.sc[0]=sa_enh; J.out[0]=CW0; J.NCb[0]=576;
        J.Wa[1]=W_sa_ct; J.Wb[1]=W_sa_qkv; J.sc[1]=sa_enh; J.out[1]=CW1; J.NCb[1]=576;
        J.Wa[2]=W_ca_cr; J.Wb[2]=W_ca_q;   J.sc[2]=ca_enh; J.out[2]=CW2; J.NCb[2]=192;
        J.Wa[3]=W_ca_ct; J.Wb[3]=W_ca_q;   J.sc[3]=ca_enh; J.out[3]=CW3; J.NCb[3]=192;
        J.Wa[4]=W_ca_cr; J.Wb[4]=W_ca_kv;  J.sc[4]=ca_enh; J.out[4]=CW4; J.NCb[4]=384;
        J.Wa[5]=W_ca_ct; J.Wb[5]=W_ca_kv;  J.sc[5]=ca_enh; J.out[5]=CW5; J.NCb[5]=384;
        int bs[7] = {0,108,216,252,288,360,432};
        for (int i = 0; i < 7; ++i) J.base[i] = bs[i];
        smallmm_all<<<432, 256, 0, stream>>>(J);
    }

    // ---- K-slabbed fp16 weights ----
    ushort* wb = (ushort*)(ws + 442368);
    ushort* WsaqH = wb;
    ushort* C0H  = WsaqH + 110592;
    ushort* C1H  = C0H + 110592;
    ushort* WcqH = C1H + 110592;
    ushort* C2H  = WcqH + 36864;
    ushort* C3H  = C2H + 36864;
    ushort* WckH = C3H + 36864;
    ushort* C4H  = WckH + 73728;
    ushort* C5H  = C4H + 73728;
    ushort* WpsH = C5H + 73728;
    ushort* WpcH = WpsH + 36864;
    ushort* chunkU = WpcH + 36864;       // = wb + 737280

    {
        WtJobs J;
        const float* Ws[11] = {W_sa_qkv, CW0, CW1, W_ca_q, CW2, CW3,
                               W_ca_kv, CW4, CW5, W_proj_sa, W_proj_ca};
        ushort* Ds[11] = {WsaqH, C0H, C1H, WcqH, C2H, C3H,
                          WckH, C4H, C5H, WpsH, WpcH};
        int NCs[11] = {576,576,576,192,192,192,384,384,384,192,192};
        int bs[12] = {0,432,864,1296,1440,1584,1728,2016,2304,2592,2736,2880};
        for (int i = 0; i < 11; ++i) { J.W[i]=Ws[i]; J.dh[i]=Ds[i]; J.NC[i]=NCs[i]; }
        for (int i = 0; i < 12; ++i) J.base[i] = bs[i];
        conv_wT_all<<<2880, 256, 0, stream>>>(J);
    }

    // ---- chunking: 188160 bytes per batch element, 64KB tail pad.
    //      Cap at 1024 so per-chunk intermediates (~192MB) fit the 256MB L3. ----
    long long avail = (long long)ws_size - 442368LL * 4 - 737280LL * 2 - 65536;
    int cbmax = (int)(avail / 188160);
    if (cbmax > 1024) cbmax = 1024;
    if (cbmax < 1) cbmax = 1;

    const long long OUT1 = 2LL * 2048 * 49 * 192;
    dim3 blk(256);

    for (int c0 = 0; c0 < 2048; c0 += cbmax) {
        int cb = (c0 + cbmax <= 2048) ? cbmax : (2048 - c0);
        int M = cb * 49;
        long long SS = (long long)M * 32;
        int gy = (M + 63) / 64;
        int cblk = (int)(((long long)M * 48 + 255) / 256);
        if (cblk > 4096) cblk = 4096;

        // 1-D grids for the swizzled GEMM: nwg = GX * gy * 2
        dim3 g1(6 * gy), g2(2 * gy), g3(4 * gy);

        // =========================== SA branch ===========================
        ushort* XtH = chunkU;                              // [6][M][32]
        ushort* XrH = XtH + (long long)cbmax * 9408;
        ushort* QtH = XrH + (long long)cbmax * 9408;       // [18][M][32]
        ushort* QrH = QtH + (long long)cbmax * 28224;
        ushort* OtH = QrH + (long long)cbmax * 28224;      // [6][M][32]
        ushort* OrH = OtH + (long long)cbmax * 9408;

        conv_x2<<<cblk, blk, 0, stream>>>(
            x_sa + (long long)c0 * 9408, x_sa + (2048LL + c0) * 9408, 9408,
            XtH, XrH, M);

        gemm_f16<576, true, false><<<g1, blk, 0, stream>>>(
            XtH, XrH, C0H, QtH, nullptr,
            XrH, XtH, C1H, QrH, nullptr,
            WsaqH, b_sa_qkv, 0, M);

        attn_f16<<<cb * 6, blk, 0, stream>>>(
            QtH, QtH + 6 * SS, QtH + 12 * SS,
            QrH, QrH + 6 * SS, QrH + 12 * SS,
            SS, rpb, lam_sa, OtH, OrH);

        gemm_f16<192, false, true><<<g2, blk, 0, stream>>>(
            OtH, nullptr, nullptr, nullptr, out + (long long)c0 * 9408,
            OrH, nullptr, nullptr, nullptr, out + (2048LL + c0) * 9408,
            WpsH, b_proj_sa, 9408, M);

        // =========================== CA branch ===========================
        ushort* CXtH = chunkU;                             // [6][M][32]
        ushort* CXrH = CXtH + (long long)cbmax * 9408;
        ushort* CQtH = CXrH + (long long)cbmax * 9408;     // [6][M][32]
        ushort* CQrH = CQtH + (long long)cbmax * 9408;
        ushort* KtH  = CQrH + (long long)cbmax * 9408;     // [12][M][32]
        ushort* KrH  = KtH + (long long)cbmax * 18816;
        ushort* COtH = KrH + (long long)cbmax * 18816;     // [6][M][32]
        ushort* COrH = COtH + (long long)cbmax * 9408;

        conv_x2<<<cblk, blk, 0, stream>>>(
            x_ca + (long long)c0 * 18816, x_ca + (long long)c0 * 18816 + 9408, 18816,
            CXtH, CXrH, M);

        gemm_f16<192, true, false><<<g2, blk, 0, stream>>>(
            CXtH, CXrH, C2H, CQtH, nullptr,
            CXrH, CXtH, C3H, CQrH, nullptr,
            WcqH, b_ca_q, 0, M);

        gemm_f16<384, true, false><<<g3, blk, 0, stream>>>(
            CXtH, CXrH, C4H, KtH, nullptr,
            CXrH, CXtH, C5H, KrH, nullptr,
            WckH, b_ca_kv, 0, M);

        attn_f16<<<cb * 6, blk, 0, stream>>>(
            CQtH, KtH, KtH + 6 * SS,
            CQrH, KrH, KrH + 6 * SS,
            SS, rpb, lam_ca, COtH, COrH);

        gemm_f16<192, false, true><<<g2, blk, 0, stream>>>(
            COtH, nullptr, nullptr, nullptr, out + OUT1 + (long long)c0 * 18816,
            COrH, nullptr, nullptr, nullptr, out + OUT1 + (long long)c0 * 18816 + 9408,
            WpcH, b_proj_ca, 18816, M);
    }
}

// Round 18
// 746.930 us; speedup vs baseline: 1.1619x; 1.0615x over previous
//
#include <hip/hip_runtime.h>
#include <cmath>

static constexpr float SCALE_ = 0.17677669529663687f; // 32^-0.5

typedef __attribute__((ext_vector_type(8))) _Float16 f16x8;
typedef __attribute__((ext_vector_type(8))) ushort u16x8;
typedef __attribute__((ext_vector_type(4))) float f32x4;

__device__ inline ushort f16u(float f) {
    union { _Float16 h; ushort u; } c;
    c.h = (_Float16)f;
    return c.u;
}

// async global->LDS, 16B per lane; LDS dest = wave-uniform base + lane*16
__device__ __forceinline__ void gld16(const ushort* g, ushort* l) {
    __builtin_amdgcn_global_load_lds(
        (const __attribute__((address_space(1))) unsigned int*)g,
        (__attribute__((address_space(3))) unsigned int*)l,
        16, 0, 0);
}

// ---------------------------------------------------------------------------
// Fused weight-combine: all 6 small GEMMs in one launch (job table).
// ---------------------------------------------------------------------------
struct SmallmmJobs {
    const float* Wa[6];
    const float* Wb[6];
    const float* sc[6];
    float*       out[6];
    int          NCb[6];
    int          base[7];
};
__global__ __launch_bounds__(256) void smallmm_all(SmallmmJobs J)
{
    int b = blockIdx.x;
    int j = 0;
    #pragma unroll
    for (int k = 1; k < 6; ++k) if (b >= J.base[k]) j = k;
    int idx = (b - J.base[j]) * 256 + threadIdx.x;
    int NCb = J.NCb[j];
    int n4  = NCb >> 2;
    int m   = idx / n4;
    int n0  = (idx - m * n4) << 2;
    if (m >= 192) return;
    const float* Wa = J.Wa[j];
    const float* Wb = J.Wb[j];
    float s = J.sc[j][0];
    float ax = 0.f, ay = 0.f, az = 0.f, aw = 0.f;
    for (int k = 0; k < 192; ++k) {
        float a = Wa[m * 192 + k];
        const float4 bv = *(const float4*)(Wb + (size_t)k * NCb + n0);
        ax += a * bv.x; ay += a * bv.y; az += a * bv.z; aw += a * bv.w;
    }
    float4 r = make_float4(ax * s, ay * s, az * s, aw * s);
    *(float4*)(J.out[j] + (size_t)m * NCb + n0) = r;
}

// ---------------------------------------------------------------------------
// Fused weight transpose+convert: f32 [192][NCsrc] -> K-slabbed transposed
// fp16 [6][dNC][32] at column offset coff (enables [Wq|Wkv] concatenation).
// ---------------------------------------------------------------------------
struct WtJobs {
    const float* W[11];
    ushort*      dh[11];
    int          NC[11];    // source NC
    int          dNC[11];   // dest NC (slab layout)
    int          coff[11];  // dest column offset
    int          base[12];
};
__global__ __launch_bounds__(256) void conv_wT_all(WtJobs J)
{
    int b = blockIdx.x;
    int j = 0;
    #pragma unroll
    for (int k = 1; k < 11; ++k) if (b >= J.base[k]) j = k;
    int idx = (b - J.base[j]) * 256 + threadIdx.x;
    int NC = J.NC[j];
    if (idx >= NC * 192) return;
    int n = idx / 192, k = idx - n * 192;
    float f = J.W[j][(long long)k * NC + n];
    long long o = ((long long)(k >> 5) * J.dNC[j] + J.coff[j] + n) * 32 + (k & 31);
    J.dh[j][o] = f16u(f);
}

// concat bias: d[0..191]=a, d[192..575]=b
__global__ __launch_bounds__(256) void concat_bias(
    const float* __restrict__ a, const float* __restrict__ b,
    float* __restrict__ d)
{
    int i = blockIdx.x * 256 + threadIdx.x;
    if (i < 192) d[i] = a[i];
    else if (i < 576) d[i] = b[i - 192];
}

// ---------------------------------------------------------------------------
// Activation f32 -> K-slabbed fp16 [6][Mc][32]; handles BOTH streams (t,r).
// ---------------------------------------------------------------------------
__global__ __launch_bounds__(256) void conv_x2(
    const float* __restrict__ src_t, const float* __restrict__ src_r,
    long long src_bs,
    ushort* __restrict__ dh_t, ushort* __restrict__ dh_r, int Mc)
{
    const long long SS = (long long)Mc * 32;
    const long long total8 = (long long)Mc * 24;
    for (long long t = (long long)blockIdx.x * 256 + threadIdx.x; t < 2 * total8;
         t += (long long)gridDim.x * 256) {
        const int second = (t >= total8);
        long long ti = second ? t - total8 : t;
        const float* src = second ? src_r : src_t;
        ushort* dh = second ? dh_r : dh_t;
        int m  = (int)(ti / 24);
        int c8 = (int)(ti - (long long)m * 24) * 8;
        int bb = m / 49, r = m - bb * 49;
        const float* sp = src + (long long)bb * src_bs + r * 192 + c8;
        float4 v0 = *(const float4*)sp;
        float4 v1 = *(const float4*)(sp + 4);
        float f[8] = {v0.x, v0.y, v0.z, v0.w, v1.x, v1.y, v1.z, v1.w};
        u16x8 h8;
        #pragma unroll
        for (int e = 0; e < 8; ++e) h8[e] = f16u(f[e]);
        long long o = (long long)(c8 >> 5) * SS + (long long)m * 32 + (c8 & 31);
        *(u16x8*)(dh + o) = h8;
    }
}

// ---------------------------------------------------------------------------
// fp16 MFMA GEMM: r13-verified optimum (772us config), byte-identical.
// 64Mx192N block, BK=64 phases (two 32-K slabs per barrier pair),
// chunked-bijective XCD swizzle. Per phase: stage A(64x64)+B(192x64) via
// global_load_lds w16 (linear dest, src chunk c ^= (row>>1)&3, same XOR on
// ds_read -> 0 conflicts) then 24 MFMAs/wave. 4 waves (2m x 2n), wave 32x96.
// LDS 32KB, 4 blocks/CU. Jobs a/b share B1 (z selects).
// F32OUT: f32 scatter; else slabbed fp16 out.
// A stage may overread past plane tail; launcher pads workspace 64KB.
// ---------------------------------------------------------------------------
template<int NC, bool DUAL, bool F32OUT>
__global__ __launch_bounds__(256, 4) void gemm_f16(
    const ushort* __restrict__ A1a, const ushort* __restrict__ A2a,
    const ushort* __restrict__ B2a, ushort* __restrict__ outHa,
    float* __restrict__ outFa,
    const ushort* __restrict__ A1b, const ushort* __restrict__ A2b,
    const ushort* __restrict__ B2b, ushort* __restrict__ outHb,
    float* __restrict__ outFb,
    const ushort* __restrict__ B1, const float* __restrict__ bias,
    long long out_bs, int M)
{
    __shared__ __align__(16) ushort AHs[2][2048];   // 2 slabs x 64 x 32
    __shared__ __align__(16) ushort BHs[2][6144];   // 2 slabs x 192 x 32

    constexpr int GX = NC / 192;
    // chunked bijective XCD swizzle (m204): XCD xc gets contiguous id range
    const int nwg = gridDim.x;
    const int orig = blockIdx.x;
    const int q8 = nwg >> 3, r8b = nwg & 7;
    const int xc = orig & 7, ix = orig >> 3;
    const int L = (xc < r8b ? xc * (q8 + 1) : r8b * (q8 + 1) + (xc - r8b) * q8) + ix;
    const int bm = L / (GX * 2);
    const int rem = L - bm * (GX * 2);
    const int bn = rem % GX;
    const int z  = rem / GX;

    const ushort* Ah1 = z ? A1b : A1a;
    const ushort* Ah2 = z ? A2b : A2a;
    const ushort* Bh2 = z ? B2b : B2a;

    const int tid = threadIdx.x;
    const int lane = tid & 63, wv = tid >> 6;
    const int wm = (wv >> 1) * 32;
    const int wn = (wv & 1) * 96;
    const int lr = lane & 15, lg = lane >> 4;
    const long long SS = (long long)M * 32;
    constexpr int NP = DUAL ? 6 : 3;   // phases of 2 slabs

    const int at_row = tid >> 2;
    const int at_c   = (tid & 3) ^ ((tid >> 3) & 3);
    const long long a_src = (long long)(bm * 64 + at_row) * 32 + at_c * 8;
    int b_src[3];
    #pragma unroll
    for (int k = 0; k < 3; ++k) {
        int t = k * 256 + tid;
        int row = t >> 2, c = (t & 3) ^ ((t >> 3) & 3);
        b_src[k] = (bn * 192 + row) * 32 + c * 8;
    }
    const int wdst = wv * 512;

    int aoff[2], boff[6];
    #pragma unroll
    for (int i = 0; i < 2; ++i) {
        int row = wm + 16 * i + lr;
        aoff[i] = (row * 4 + (lg ^ ((row >> 1) & 3))) * 8;
    }
    #pragma unroll
    for (int j = 0; j < 6; ++j) {
        int row = wn + 16 * j + lr;
        boff[j] = (row * 4 + (lg ^ ((row >> 1) & 3))) * 8;
    }

    f32x4 acc[2][6] = {};

    #pragma unroll
    for (int p = 0; p < NP; ++p) {
        // stage two slabs into the two LDS halves
        #pragma unroll
        for (int hbf = 0; hbf < 2; ++hbf) {
            const int s = 2 * p + hbf;
            const int k6 = (s < 6) ? s : s - 6;
            const ushort* AHp = (!DUAL || s < 6) ? Ah1 : Ah2;
            const ushort* BHp = (!DUAL || s < 6) ? B1  : Bh2;
            const long long asb = (long long)k6 * SS;
            const int bsb = k6 * (NC * 32);
            gld16(AHp + asb + a_src, AHs[hbf] + wdst);
            #pragma unroll
            for (int k = 0; k < 3; ++k)
                gld16(BHp + bsb + b_src[k], BHs[hbf] + k * 2048 + wdst);
        }
        __syncthreads();   // drain vmcnt -> both slabs visible

        #pragma unroll
        for (int hbf = 0; hbf < 2; ++hbf) {
            f16x8 ah[2];
            #pragma unroll
            for (int i = 0; i < 2; ++i)
                ah[i] = *(const f16x8*)&AHs[hbf][aoff[i]];
            #pragma unroll
            for (int j = 0; j < 6; ++j) {
                f16x8 bh = *(const f16x8*)&BHs[hbf][boff[j]];
                #pragma unroll
                for (int i = 0; i < 2; ++i)
                    acc[i][j] = __builtin_amdgcn_mfma_f32_16x16x32_f16(ah[i], bh, acc[i][j], 0, 0, 0);
            }
        }
        __syncthreads();   // all reads done before next stage overwrites
    }

    #pragma unroll
    for (int j = 0; j < 6; ++j) {
        const int c = bn * 192 + wn + 16 * j + lr;
        const float bv = bias ? bias[c] : 0.f;
        #pragma unroll
        for (int i = 0; i < 2; ++i)
            #pragma unroll
            for (int r = 0; r < 4; ++r) {
                int m = bm * 64 + wm + 16 * i + 4 * lg + r;
                if (m < M) {
                    float f = acc[i][j][r] + bv;
                    if constexpr (F32OUT) {
                        float* outF = z ? outFb : outFa;
                        int b2 = m / 49, r2 = m - b2 * 49;
                        outF[(long long)b2 * out_bs + r2 * 192 + c] = f;
                    } else {
                        ushort* outH = z ? outHb : outHa;
                        long long o = (long long)(c >> 5) * SS + (long long)m * 32 + (c & 31);
                        outH[o] = f16u(f);
                    }
                }
            }
    }
}

// ---------------------------------------------------------------------------
// MFMA differential attention on K-slabbed fp16 planes (r13-verified, no
// setprio — r17 A/B showed neutral-to-negative).
// ---------------------------------------------------------------------------
__global__ __launch_bounds__(256, 4) void attn_f16(
    const ushort* __restrict__ qT, const ushort* __restrict__ kT,
    const ushort* __restrict__ vT,
    const ushort* __restrict__ qR, const ushort* __restrict__ kR,
    const ushort* __restrict__ vR,
    long long SS,
    const float* __restrict__ rpb, const float* __restrict__ lam_ptr,
    ushort* __restrict__ otH, ushort* __restrict__ orH)
{
    __shared__ __align__(16) ushort Pth[64][72];
    __shared__ __align__(16) ushort Vs[2][32][70];  // [stream][d][j]
    __shared__ float bias_s[169];

    const int tid = threadIdx.x;
    const int bb = blockIdx.x / 6;
    const int h  = blockIdx.x - bb * 6;
    const int lane = tid & 63;
    const int w  = tid >> 6;
    const int li = lane & 15;
    const int lg = lane >> 4;
    const long long rowbase = (long long)bb * 49 * 32;
    const long long hb = (long long)h * SS + rowbase;

    for (int idx = tid; idx < 169; idx += 256) bias_s[idx] = rpb[idx * 6 + h];

    {
        const ushort* vsrc[2] = {vT + hb, vR + hb};
        for (int c = tid; c < 392; c += 256) {
            int s  = c / 196;
            int r2 = c - s * 196;
            int j  = r2 >> 2;
            int d4 = (r2 & 3) * 8;
            u16x8 v = *(const u16x8*)(vsrc[s] + j * 32 + d4);
            #pragma unroll
            for (int e = 0; e < 8; ++e) Vs[s][d4 + e][j] = v[e];
        }
        for (int c = tid; c < 2 * 32 * 21; c += 256) {
            int s  = c / (32 * 21);
            int r1 = c - s * (32 * 21);
            int d  = r1 / 21;
            int j  = 49 + (r1 - d * 21);
            Vs[s][d][j] = 0;
        }
    }

    float lraw = lam_ptr[0];
    float lam = 1.f / (1.f + __expf(-lraw));
    lam = fminf(fmaxf(lam, 0.01f), 0.99f);

    const int irow = min(w * 16 + li, 48);

    f32x4 st[2][4];
    #pragma unroll
    for (int s = 0; s < 2; ++s) {
        const ushort* qb = (s ? qR : qT) + hb;
        const ushort* kb = (s ? kR : kT) + hb;
        f16x8 qh = *(const f16x8*)(qb + irow * 32 + 8 * lg);
        #pragma unroll
        for (int jt = 0; jt < 4; ++jt) {
            int jr = jt * 16 + li; if (jr > 48) jr = 48;
            f16x8 kh = *(const f16x8*)(kb + jr * 32 + 8 * lg);
            f32x4 c = {};
            c = __builtin_amdgcn_mfma_f32_16x16x32_f16(kh, qh, c, 0, 0, 0);
            st[s][jt] = c;
        }
    }
    __syncthreads();   // bias_s + Vs staged (only barrier)

    const int ri = (irow * 9363) >> 16;
    const int ci = irow - 7 * ri;
    float bias_v[4][4];
    #pragma unroll
    for (int jt = 0; jt < 4; ++jt)
        #pragma unroll
        for (int r = 0; r < 4; ++r) {
            int j = jt * 16 + 4 * lg + r;
            int jc = (j < 49) ? j : 48;
            int rj = (jc * 9363) >> 16;
            int cj = jc - 7 * rj;
            bias_v[jt][r] = bias_s[(ri - rj + 6) * 13 + (ci - cj + 6)];
        }

    float p[2][4][4];
    #pragma unroll
    for (int s = 0; s < 2; ++s) {
        float m = -1e30f;
        #pragma unroll
        for (int jt = 0; jt < 4; ++jt)
            #pragma unroll
            for (int r = 0; r < 4; ++r) {
                int j = jt * 16 + 4 * lg + r;
                float sv = (j < 49) ? (st[s][jt][r] * SCALE_ + bias_v[jt][r]) : -1e30f;
                p[s][jt][r] = sv;
                m = fmaxf(m, sv);
            }
        m = fmaxf(m, __shfl_xor(m, 16));
        m = fmaxf(m, __shfl_xor(m, 32));
        float sum = 0.f;
        #pragma unroll
        for (int jt = 0; jt < 4; ++jt)
            #pragma unroll
            for (int r = 0; r < 4; ++r) {
                float e = __expf(p[s][jt][r] - m);
                p[s][jt][r] = e;
                sum += e;
            }
        sum += __shfl_xor(sum, 16);
        sum += __shfl_xor(sum, 32);
        float inv = 1.f / sum;
        #pragma unroll
        for (int jt = 0; jt < 4; ++jt)
            #pragma unroll
            for (int r = 0; r < 4; ++r)
                p[s][jt][r] *= inv;
    }

    const int prow = w * 16 + li;
    #pragma unroll
    for (int s = 0; s < 2; ++s) {
        #pragma unroll
        for (int jt = 0; jt < 4; ++jt) {
            ushort4 h4;
            #pragma unroll
            for (int r = 0; r < 4; ++r) {
                float at = p[0][jt][r], ar = p[1][jt][r];
                float f = (s == 0) ? (at - lam * ar) : (ar - lam * at);
                ((ushort*)&h4)[r] = f16u(f);
            }
            *(ushort4*)&Pth[prow][jt * 16 + 4 * lg] = h4;
        }

        f32x4 acc[2] = {};
        #pragma unroll
        for (int ks = 0; ks < 2; ++ks) {
            f16x8 pa = *(const f16x8*)&Pth[prow][ks * 32 + 8 * lg];
            #pragma unroll
            for (int dt = 0; dt < 2; ++dt) {
                f16x8 vh = *(const f16x8*)&Vs[s][dt * 16 + li][ks * 32 + 8 * lg];
                acc[dt] = __builtin_amdgcn_mfma_f32_16x16x32_f16(pa, vh, acc[dt], 0, 0, 0);
            }
        }
        ushort* oph = s ? orH : otH;
        #pragma unroll
        for (int dt = 0; dt < 2; ++dt)
            #pragma unroll
            for (int r = 0; r < 4; ++r) {
                int i = w * 16 + 4 * lg + r;
                if (i < 49) {
                    long long o = (long long)h * SS + rowbase + (long long)i * 32 + dt * 16 + li;
                    oph[o] = f16u(acc[dt][r]);
                }
            }
    }
}

// ---------------------------------------------------------------------------
extern "C" void kernel_launch(void* const* d_in, const int* in_sizes, int n_in,
                              void* d_out, int out_size, void* d_ws, size_t ws_size,
                              hipStream_t stream)
{
    const float* x_sa      = (const float*)d_in[0];
    const float* x_ca      = (const float*)d_in[1];
    const float* lam_sa    = (const float*)d_in[2];
    const float* lam_ca    = (const float*)d_in[3];
    const float* sa_enh    = (const float*)d_in[4];
    const float* ca_enh    = (const float*)d_in[5];
    const float* W_sa_qkv  = (const float*)d_in[6];
    const float* b_sa_qkv  = (const float*)d_in[7];
    const float* W_sa_ct   = (const float*)d_in[8];
    const float* W_sa_cr   = (const float*)d_in[9];
    const float* W_ca_q    = (const float*)d_in[10];
    const float* b_ca_q    = (const float*)d_in[11];
    const float* W_ca_kv   = (const float*)d_in[12];
    const float* b_ca_kv   = (const float*)d_in[13];
    const float* W_ca_ct   = (const float*)d_in[14];
    const float* W_ca_cr   = (const float*)d_in[15];
    const float* rpb       = (const float*)d_in[16];
    const float* W_proj_sa = (const float*)d_in[17];
    const float* b_proj_sa = (const float*)d_in[18];
    const float* W_proj_ca = (const float*)d_in[19];
    const float* b_proj_ca = (const float*)d_in[20];
    float* out = (float*)d_out;
    float* ws  = (float*)d_ws;

    // ---- f32 combined-weight temps ----
    float* CW0 = ws;             // 192x576
    float* CW1 = CW0 + 110592;
    float* CW2 = CW1 + 110592;   // 192x192
    float* CW3 = CW2 + 36864;
    float* CW4 = CW3 + 36864;    // 192x384
    float* CW5 = CW4 + 73728;
    float* bqkv_ca = CW5 + 73728;   // 576 concat bias
    // float region total: 442368 + 576 floats

    {
        SmallmmJobs J;
        J.Wa[0]=W_sa_cr; J.Wb[0]=W_sa_qkv; J.sc[0]=sa_enh; J.out[0]=CW0; J.NCb[0]=576;
        J.Wa[1]=W_sa_ct; J.Wb[1]=W_sa_qkv; J.sc[1]=sa_enh; J.out[1]=CW1; J.NCb[1]=576;
        J.Wa[2]=W_ca_cr; J.Wb[2]=W_ca_q;   J.sc[2]=ca_enh; J.out[2]=CW2; J.NCb[2]=192;
        J.Wa[3]=W_ca_ct; J.Wb[3]=W_ca_q;   J.sc[3]=ca_enh; J.out[3]=CW3; J.NCb[3]=192;
        J.Wa[4]=W_ca_cr; J.Wb[4]=W_ca_kv;  J.sc[4]=ca_enh; J.out[4]=CW4; J.NCb[4]=384;
        J.Wa[5]=W_ca_ct; J.Wb[5]=W_ca_kv;  J.sc[5]=ca_enh; J.out[5]=CW5; J.NCb[5]=384;
        int bs[7] = {0,108,216,252,288,360,432};
        for (int i = 0; i < 7; ++i) J.base[i] = bs[i];
        smallmm_all<<<432, 256, 0, stream>>>(J);
    }
    concat_bias<<<3, 256, 0, stream>>>(b_ca_q, b_ca_kv, bqkv_ca);

    // ---- K-slabbed fp16 weights (CA q+kv concatenated into NC=576) ----
    ushort* wb = (ushort*)(ws + 442944);
    ushort* WsaqH  = wb;                    // [6][576][32]
    ushort* C0H    = WsaqH + 110592;
    ushort* C1H    = C0H + 110592;
    ushort* WcqkvH = C1H + 110592;          // [6][576][32] = [Wq|Wkv]
    ushort* C24H   = WcqkvH + 110592;       // [C2|C4]
    ushort* C35H   = C24H + 110592;         // [C3|C5]
    ushort* WpsH   = C35H + 110592;         // [6][192][32]
    ushort* WpcH   = WpsH + 36864;
    ushort* chunkU = WpcH + 36864;          // = wb + 737280

    {
        WtJobs J;
        const float* Ws[11] = {W_sa_qkv, CW0, CW1,
                               W_ca_q, CW2, CW3,
                               W_ca_kv, CW4, CW5,
                               W_proj_sa, W_proj_ca};
        ushort* Ds[11] = {WsaqH, C0H, C1H,
                          WcqkvH, C24H, C35H,
                          WcqkvH, C24H, C35H,
                          WpsH, WpcH};
        int NCs[11]  = {576,576,576, 192,192,192, 384,384,384, 192,192};
        int dNCs[11] = {576,576,576, 576,576,576, 576,576,576, 192,192};
        int coffs[11]= {0,0,0, 0,0,0, 192,192,192, 0,0};
        int bs[12] = {0,432,864,1296,1440,1584,1728,2016,2304,2592,2736,2880};
        for (int i = 0; i < 11; ++i) {
            J.W[i]=Ws[i]; J.dh[i]=Ds[i]; J.NC[i]=NCs[i];
            J.dNC[i]=dNCs[i]; J.coff[i]=coffs[i];
        }
        for (int i = 0; i < 12; ++i) J.base[i] = bs[i];
        conv_wT_all<<<2880, 256, 0, stream>>>(J);
    }

    // ---- chunking: 188160 bytes per batch element, 64KB tail pad.
    //      Cap at 1024 so per-chunk intermediates (~192MB) fit the 256MB L3. ----
    long long avail = (long long)ws_size - 442944LL * 4 - 737280LL * 2 - 65536;
    int cbmax = (int)(avail / 188160);
    if (cbmax > 1024) cbmax = 1024;
    if (cbmax < 1) cbmax = 1;

    const long long OUT1 = 2LL * 2048 * 49 * 192;
    dim3 blk(256);

    for (int c0 = 0; c0 < 2048; c0 += cbmax) {
        int cb = (c0 + cbmax <= 2048) ? cbmax : (2048 - c0);
        int M = cb * 49;
        long long SS = (long long)M * 32;
        int gy = (M + 63) / 64;
        int cblk = (int)(((long long)M * 48 + 255) / 256);
        if (cblk > 4096) cblk = 4096;

        // 1-D grids for the swizzled GEMM: nwg = GX * gy * 2
        dim3 g1(6 * gy), g2(2 * gy);

        // =========================== SA branch ===========================
        ushort* XtH = chunkU;                              // [6][M][32]
        ushort* XrH = XtH + (long long)cbmax * 9408;
        ushort* QtH = XrH + (long long)cbmax * 9408;       // [18][M][32]
        ushort* QrH = QtH + (long long)cbmax * 28224;
        ushort* OtH = QrH + (long long)cbmax * 28224;      // [6][M][32]
        ushort* OrH = OtH + (long long)cbmax * 9408;

        conv_x2<<<cblk, blk, 0, stream>>>(
            x_sa + (long long)c0 * 9408, x_sa + (2048LL + c0) * 9408, 9408,
            XtH, XrH, M);

        gemm_f16<576, true, false><<<g1, blk, 0, stream>>>(
            XtH, XrH, C0H, QtH, nullptr,
            XrH, XtH, C1H, QrH, nullptr,
            WsaqH, b_sa_qkv, 0, M);

        attn_f16<<<cb * 6, blk, 0, stream>>>(
            QtH, QtH + 6 * SS, QtH + 12 * SS,
            QrH, QrH + 6 * SS, QrH + 12 * SS,
            SS, rpb, lam_sa, OtH, OrH);

        gemm_f16<192, false, true><<<g2, blk, 0, stream>>>(
            OtH, nullptr, nullptr, nullptr, out + (long long)c0 * 9408,
            OrH, nullptr, nullptr, nullptr, out + (2048LL + c0) * 9408,
            WpsH, b_proj_sa, 9408, M);

        // =========================== CA branch ===========================
        ushort* CXtH = chunkU;                             // [6][M][32]
        ushort* CXrH = CXtH + (long long)cbmax * 9408;
        ushort* CQtH = CXrH + (long long)cbmax * 9408;     // [18][M][32] qkv
        ushort* CQrH = CQtH + (long long)cbmax * 28224;
        ushort* COtH = CQrH + (long long)cbmax * 28224;    // [6][M][32]
        ushort* COrH = COtH + (long long)cbmax * 9408;

        conv_x2<<<cblk, blk, 0, stream>>>(
            x_ca + (long long)c0 * 18816, x_ca + (long long)c0 * 18816 + 9408, 18816,
            CXtH, CXrH, M);

        // qkv_t = xt@[Wq|Wkv] + xr@[C2|C4] ; qkv_r = xr@[Wq|Wkv] + xt@[C3|C5]
        gemm_f16<576, true, false><<<g1, blk, 0, stream>>>(
            CXtH, CXrH, C24H, CQtH, nullptr,
            CXrH, CXtH, C35H, CQrH, nullptr,
            WcqkvH, bqkv_ca, 0, M);

        attn_f16<<<cb * 6, blk, 0, stream>>>(
            CQtH, CQtH + 6 * SS, CQtH + 12 * SS,
            CQrH, CQrH + 6 * SS, CQrH + 12 * SS,
            SS, rpb, lam_ca, COtH, COrH);

        gemm_f16<192, false, true><<<g2, blk, 0, stream>>>(
            COtH, nullptr, nullptr, nullptr, out + OUT1 + (long long)c0 * 18816,
            COrH, nullptr, nullptr, nullptr, out + OUT1 + (long long)c0 * 18816 + 9408,
            WpcH, b_proj_ca, 18816, M);
    }
}

// Round 19
// 746.444 us; speedup vs baseline: 1.1627x; 1.0007x over previous
//
#include <hip/hip_runtime.h>
#include <cmath>

static constexpr float SCALE_ = 0.17677669529663687f; // 32^-0.5

typedef __attribute__((ext_vector_type(8))) _Float16 f16x8;
typedef __attribute__((ext_vector_type(8))) ushort u16x8;
typedef __attribute__((ext_vector_type(4))) float f32x4;

__device__ inline ushort f16u(float f) {
    union { _Float16 h; ushort u; } c;
    c.h = (_Float16)f;
    return c.u;
}

// async global->LDS, 16B per lane; LDS dest = wave-uniform base + lane*16
__device__ __forceinline__ void gld16(const ushort* g, ushort* l) {
    __builtin_amdgcn_global_load_lds(
        (const __attribute__((address_space(1))) unsigned int*)g,
        (__attribute__((address_space(3))) unsigned int*)l,
        16, 0, 0);
}

// ---------------------------------------------------------------------------
// Fused weight-combine: all 6 small GEMMs in one launch (job table).
// ---------------------------------------------------------------------------
struct SmallmmJobs {
    const float* Wa[6];
    const float* Wb[6];
    const float* sc[6];
    float*       out[6];
    int          NCb[6];
    int          base[7];
};
__global__ __launch_bounds__(256) void smallmm_all(SmallmmJobs J)
{
    int b = blockIdx.x;
    int j = 0;
    #pragma unroll
    for (int k = 1; k < 6; ++k) if (b >= J.base[k]) j = k;
    int idx = (b - J.base[j]) * 256 + threadIdx.x;
    int NCb = J.NCb[j];
    int n4  = NCb >> 2;
    int m   = idx / n4;
    int n0  = (idx - m * n4) << 2;
    if (m >= 192) return;
    const float* Wa = J.Wa[j];
    const float* Wb = J.Wb[j];
    float s = J.sc[j][0];
    float ax = 0.f, ay = 0.f, az = 0.f, aw = 0.f;
    for (int k = 0; k < 192; ++k) {
        float a = Wa[m * 192 + k];
        const float4 bv = *(const float4*)(Wb + (size_t)k * NCb + n0);
        ax += a * bv.x; ay += a * bv.y; az += a * bv.z; aw += a * bv.w;
    }
    float4 r = make_float4(ax * s, ay * s, az * s, aw * s);
    *(float4*)(J.out[j] + (size_t)m * NCb + n0) = r;
}

// ---------------------------------------------------------------------------
// Fused weight transpose+convert: f32 [192][NCsrc] -> K-slabbed transposed
// fp16 [6][dNC][32] at column offset coff (enables [Wq|Wkv] concatenation).
// ---------------------------------------------------------------------------
struct WtJobs {
    const float* W[11];
    ushort*      dh[11];
    int          NC[11];    // source NC
    int          dNC[11];   // dest NC (slab layout)
    int          coff[11];  // dest column offset
    int          base[12];
};
__global__ __launch_bounds__(256) void conv_wT_all(WtJobs J)
{
    int b = blockIdx.x;
    int j = 0;
    #pragma unroll
    for (int k = 1; k < 11; ++k) if (b >= J.base[k]) j = k;
    int idx = (b - J.base[j]) * 256 + threadIdx.x;
    int NC = J.NC[j];
    if (idx >= NC * 192) return;
    int n = idx / 192, k = idx - n * 192;
    float f = J.W[j][(long long)k * NC + n];
    long long o = ((long long)(k >> 5) * J.dNC[j] + J.coff[j] + n) * 32 + (k & 31);
    J.dh[j][o] = f16u(f);
}

// concat bias: d[0..191]=a, d[192..575]=b
__global__ __launch_bounds__(256) void concat_bias(
    const float* __restrict__ a, const float* __restrict__ b,
    float* __restrict__ d)
{
    int i = blockIdx.x * 256 + threadIdx.x;
    if (i < 192) d[i] = a[i];
    else if (i < 576) d[i] = b[i - 192];
}

// ---------------------------------------------------------------------------
// Activation f32 -> K-slabbed fp16 [6][Mc][32]; handles BOTH streams (t,r).
// ---------------------------------------------------------------------------
__global__ __launch_bounds__(256) void conv_x2(
    const float* __restrict__ src_t, const float* __restrict__ src_r,
    long long src_bs,
    ushort* __restrict__ dh_t, ushort* __restrict__ dh_r, int Mc)
{
    const long long SS = (long long)Mc * 32;
    const long long total8 = (long long)Mc * 24;
    for (long long t = (long long)blockIdx.x * 256 + threadIdx.x; t < 2 * total8;
         t += (long long)gridDim.x * 256) {
        const int second = (t >= total8);
        long long ti = second ? t - total8 : t;
        const float* src = second ? src_r : src_t;
        ushort* dh = second ? dh_r : dh_t;
        int m  = (int)(ti / 24);
        int c8 = (int)(ti - (long long)m * 24) * 8;
        int bb = m / 49, r = m - bb * 49;
        const float* sp = src + (long long)bb * src_bs + r * 192 + c8;
        float4 v0 = *(const float4*)sp;
        float4 v1 = *(const float4*)(sp + 4);
        float f[8] = {v0.x, v0.y, v0.z, v0.w, v1.x, v1.y, v1.z, v1.w};
        u16x8 h8;
        #pragma unroll
        for (int e = 0; e < 8; ++e) h8[e] = f16u(f[e]);
        long long o = (long long)(c8 >> 5) * SS + (long long)m * 32 + (c8 & 31);
        *(u16x8*)(dh + o) = h8;
    }
}

// ---------------------------------------------------------------------------
// fp16 MFMA GEMM: r13/r18-verified structure; this round's single variable:
// __launch_bounds__(256, 5) -> 5 blocks/CU (5 x 32KB = 160KB LDS exactly;
// VGPR 48 << 102 budget at 5 waves/SIMD). More resident waves to overlap
// the per-phase vmcnt(0) drain. Everything else byte-identical to r18.
// ---------------------------------------------------------------------------
template<int NC, bool DUAL, bool F32OUT>
__global__ __launch_bounds__(256, 5) void gemm_f16(
    const ushort* __restrict__ A1a, const ushort* __restrict__ A2a,
    const ushort* __restrict__ B2a, ushort* __restrict__ outHa,
    float* __restrict__ outFa,
    const ushort* __restrict__ A1b, const ushort* __restrict__ A2b,
    const ushort* __restrict__ B2b, ushort* __restrict__ outHb,
    float* __restrict__ outFb,
    const ushort* __restrict__ B1, const float* __restrict__ bias,
    long long out_bs, int M)
{
    __shared__ __align__(16) ushort AHs[2][2048];   // 2 slabs x 64 x 32
    __shared__ __align__(16) ushort BHs[2][6144];   // 2 slabs x 192 x 32

    constexpr int GX = NC / 192;
    // chunked bijective XCD swizzle (m204): XCD xc gets contiguous id range
    const int nwg = gridDim.x;
    const int orig = blockIdx.x;
    const int q8 = nwg >> 3, r8b = nwg & 7;
    const int xc = orig & 7, ix = orig >> 3;
    const int L = (xc < r8b ? xc * (q8 + 1) : r8b * (q8 + 1) + (xc - r8b) * q8) + ix;
    const int bm = L / (GX * 2);
    const int rem = L - bm * (GX * 2);
    const int bn = rem % GX;
    const int z  = rem / GX;

    const ushort* Ah1 = z ? A1b : A1a;
    const ushort* Ah2 = z ? A2b : A2a;
    const ushort* Bh2 = z ? B2b : B2a;

    const int tid = threadIdx.x;
    const int lane = tid & 63, wv = tid >> 6;
    const int wm = (wv >> 1) * 32;
    const int wn = (wv & 1) * 96;
    const int lr = lane & 15, lg = lane >> 4;
    const long long SS = (long long)M * 32;
    constexpr int NP = DUAL ? 6 : 3;   // phases of 2 slabs

    const int at_row = tid >> 2;
    const int at_c   = (tid & 3) ^ ((tid >> 3) & 3);
    const long long a_src = (long long)(bm * 64 + at_row) * 32 + at_c * 8;
    int b_src[3];
    #pragma unroll
    for (int k = 0; k < 3; ++k) {
        int t = k * 256 + tid;
        int row = t >> 2, c = (t & 3) ^ ((t >> 3) & 3);
        b_src[k] = (bn * 192 + row) * 32 + c * 8;
    }
    const int wdst = wv * 512;

    int aoff[2], boff[6];
    #pragma unroll
    for (int i = 0; i < 2; ++i) {
        int row = wm + 16 * i + lr;
        aoff[i] = (row * 4 + (lg ^ ((row >> 1) & 3))) * 8;
    }
    #pragma unroll
    for (int j = 0; j < 6; ++j) {
        int row = wn + 16 * j + lr;
        boff[j] = (row * 4 + (lg ^ ((row >> 1) & 3))) * 8;
    }

    f32x4 acc[2][6] = {};

    #pragma unroll
    for (int p = 0; p < NP; ++p) {
        // stage two slabs into the two LDS halves
        #pragma unroll
        for (int hbf = 0; hbf < 2; ++hbf) {
            const int s = 2 * p + hbf;
            const int k6 = (s < 6) ? s : s - 6;
            const ushort* AHp = (!DUAL || s < 6) ? Ah1 : Ah2;
            const ushort* BHp = (!DUAL || s < 6) ? B1  : Bh2;
            const long long asb = (long long)k6 * SS;
            const int bsb = k6 * (NC * 32);
            gld16(AHp + asb + a_src, AHs[hbf] + wdst);
            #pragma unroll
            for (int k = 0; k < 3; ++k)
                gld16(BHp + bsb + b_src[k], BHs[hbf] + k * 2048 + wdst);
        }
        __syncthreads();   // drain vmcnt -> both slabs visible

        #pragma unroll
        for (int hbf = 0; hbf < 2; ++hbf) {
            f16x8 ah[2];
            #pragma unroll
            for (int i = 0; i < 2; ++i)
                ah[i] = *(const f16x8*)&AHs[hbf][aoff[i]];
            #pragma unroll
            for (int j = 0; j < 6; ++j) {
                f16x8 bh = *(const f16x8*)&BHs[hbf][boff[j]];
                #pragma unroll
                for (int i = 0; i < 2; ++i)
                    acc[i][j] = __builtin_amdgcn_mfma_f32_16x16x32_f16(ah[i], bh, acc[i][j], 0, 0, 0);
            }
        }
        __syncthreads();   // all reads done before next stage overwrites
    }

    #pragma unroll
    for (int j = 0; j < 6; ++j) {
        const int c = bn * 192 + wn + 16 * j + lr;
        const float bv = bias ? bias[c] : 0.f;
        #pragma unroll
        for (int i = 0; i < 2; ++i)
            #pragma unroll
            for (int r = 0; r < 4; ++r) {
                int m = bm * 64 + wm + 16 * i + 4 * lg + r;
                if (m < M) {
                    float f = acc[i][j][r] + bv;
                    if constexpr (F32OUT) {
                        float* outF = z ? outFb : outFa;
                        int b2 = m / 49, r2 = m - b2 * 49;
                        outF[(long long)b2 * out_bs + r2 * 192 + c] = f;
                    } else {
                        ushort* outH = z ? outHb : outHa;
                        long long o = (long long)(c >> 5) * SS + (long long)m * 32 + (c & 31);
                        outH[o] = f16u(f);
                    }
                }
            }
    }
}

// ---------------------------------------------------------------------------
// MFMA differential attention on K-slabbed fp16 planes (r13-verified).
// ---------------------------------------------------------------------------
__global__ __launch_bounds__(256, 4) void attn_f16(
    const ushort* __restrict__ qT, const ushort* __restrict__ kT,
    const ushort* __restrict__ vT,
    const ushort* __restrict__ qR, const ushort* __restrict__ kR,
    const ushort* __restrict__ vR,
    long long SS,
    const float* __restrict__ rpb, const float* __restrict__ lam_ptr,
    ushort* __restrict__ otH, ushort* __restrict__ orH)
{
    __shared__ __align__(16) ushort Pth[64][72];
    __shared__ __align__(16) ushort Vs[2][32][70];  // [stream][d][j]
    __shared__ float bias_s[169];

    const int tid = threadIdx.x;
    const int bb = blockIdx.x / 6;
    const int h  = blockIdx.x - bb * 6;
    const int lane = tid & 63;
    const int w  = tid >> 6;
    const int li = lane & 15;
    const int lg = lane >> 4;
    const long long rowbase = (long long)bb * 49 * 32;
    const long long hb = (long long)h * SS + rowbase;

    for (int idx = tid; idx < 169; idx += 256) bias_s[idx] = rpb[idx * 6 + h];

    {
        const ushort* vsrc[2] = {vT + hb, vR + hb};
        for (int c = tid; c < 392; c += 256) {
            int s  = c / 196;
            int r2 = c - s * 196;
            int j  = r2 >> 2;
            int d4 = (r2 & 3) * 8;
            u16x8 v = *(const u16x8*)(vsrc[s] + j * 32 + d4);
            #pragma unroll
            for (int e = 0; e < 8; ++e) Vs[s][d4 + e][j] = v[e];
        }
        for (int c = tid; c < 2 * 32 * 21; c += 256) {
            int s  = c / (32 * 21);
            int r1 = c - s * (32 * 21);
            int d  = r1 / 21;
            int j  = 49 + (r1 - d * 21);
            Vs[s][d][j] = 0;
        }
    }

    float lraw = lam_ptr[0];
    float lam = 1.f / (1.f + __expf(-lraw));
    lam = fminf(fmaxf(lam, 0.01f), 0.99f);

    const int irow = min(w * 16 + li, 48);

    f32x4 st[2][4];
    #pragma unroll
    for (int s = 0; s < 2; ++s) {
        const ushort* qb = (s ? qR : qT) + hb;
        const ushort* kb = (s ? kR : kT) + hb;
        f16x8 qh = *(const f16x8*)(qb + irow * 32 + 8 * lg);
        #pragma unroll
        for (int jt = 0; jt < 4; ++jt) {
            int jr = jt * 16 + li; if (jr > 48) jr = 48;
            f16x8 kh = *(const f16x8*)(kb + jr * 32 + 8 * lg);
            f32x4 c = {};
            c = __builtin_amdgcn_mfma_f32_16x16x32_f16(kh, qh, c, 0, 0, 0);
            st[s][jt] = c;
        }
    }
    __syncthreads();   // bias_s + Vs staged (only barrier)

    const int ri = (irow * 9363) >> 16;
    const int ci = irow - 7 * ri;
    float bias_v[4][4];
    #pragma unroll
    for (int jt = 0; jt < 4; ++jt)
        #pragma unroll
        for (int r = 0; r < 4; ++r) {
            int j = jt * 16 + 4 * lg + r;
            int jc = (j < 49) ? j : 48;
            int rj = (jc * 9363) >> 16;
            int cj = jc - 7 * rj;
            bias_v[jt][r] = bias_s[(ri - rj + 6) * 13 + (ci - cj + 6)];
        }

    float p[2][4][4];
    #pragma unroll
    for (int s = 0; s < 2; ++s) {
        float m = -1e30f;
        #pragma unroll
        for (int jt = 0; jt < 4; ++jt)
            #pragma unroll
            for (int r = 0; r < 4; ++r) {
                int j = jt * 16 + 4 * lg + r;
                float sv = (j < 49) ? (st[s][jt][r] * SCALE_ + bias_v[jt][r]) : -1e30f;
                p[s][jt][r] = sv;
                m = fmaxf(m, sv);
            }
        m = fmaxf(m, __shfl_xor(m, 16));
        m = fmaxf(m, __shfl_xor(m, 32));
        float sum = 0.f;
        #pragma unroll
        for (int jt = 0; jt < 4; ++jt)
            #pragma unroll
            for (int r = 0; r < 4; ++r) {
                float e = __expf(p[s][jt][r] - m);
                p[s][jt][r] = e;
                sum += e;
            }
        sum += __shfl_xor(sum, 16);
        sum += __shfl_xor(sum, 32);
        float inv = 1.f / sum;
        #pragma unroll
        for (int jt = 0; jt < 4; ++jt)
            #pragma unroll
            for (int r = 0; r < 4; ++r)
                p[s][jt][r] *= inv;
    }

    const int prow = w * 16 + li;
    #pragma unroll
    for (int s = 0; s < 2; ++s) {
        #pragma unroll
        for (int jt = 0; jt < 4; ++jt) {
            ushort4 h4;
            #pragma unroll
            for (int r = 0; r < 4; ++r) {
                float at = p[0][jt][r], ar = p[1][jt][r];
                float f = (s == 0) ? (at - lam * ar) : (ar - lam * at);
                ((ushort*)&h4)[r] = f16u(f);
            }
            *(ushort4*)&Pth[prow][jt * 16 + 4 * lg] = h4;
        }

        f32x4 acc[2] = {};
        #pragma unroll
        for (int ks = 0; ks < 2; ++ks) {
            f16x8 pa = *(const f16x8*)&Pth[prow][ks * 32 + 8 * lg];
            #pragma unroll
            for (int dt = 0; dt < 2; ++dt) {
                f16x8 vh = *(const f16x8*)&Vs[s][dt * 16 + li][ks * 32 + 8 * lg];
                acc[dt] = __builtin_amdgcn_mfma_f32_16x16x32_f16(pa, vh, acc[dt], 0, 0, 0);
            }
        }
        ushort* oph = s ? orH : otH;
        #pragma unroll
        for (int dt = 0; dt < 2; ++dt)
            #pragma unroll
            for (int r = 0; r < 4; ++r) {
                int i = w * 16 + 4 * lg + r;
                if (i < 49) {
                    long long o = (long long)h * SS + rowbase + (long long)i * 32 + dt * 16 + li;
                    oph[o] = f16u(acc[dt][r]);
                }
            }
    }
}

// ---------------------------------------------------------------------------
extern "C" void kernel_launch(void* const* d_in, const int* in_sizes, int n_in,
                              void* d_out, int out_size, void* d_ws, size_t ws_size,
                              hipStream_t stream)
{
    const float* x_sa      = (const float*)d_in[0];
    const float* x_ca      = (const float*)d_in[1];
    const float* lam_sa    = (const float*)d_in[2];
    const float* lam_ca    = (const float*)d_in[3];
    const float* sa_enh    = (const float*)d_in[4];
    const float* ca_enh    = (const float*)d_in[5];
    const float* W_sa_qkv  = (const float*)d_in[6];
    const float* b_sa_qkv  = (const float*)d_in[7];
    const float* W_sa_ct   = (const float*)d_in[8];
    const float* W_sa_cr   = (const float*)d_in[9];
    const float* W_ca_q    = (const float*)d_in[10];
    const float* b_ca_q    = (const float*)d_in[11];
    const float* W_ca_kv   = (const float*)d_in[12];
    const float* b_ca_kv   = (const float*)d_in[13];
    const float* W_ca_ct   = (const float*)d_in[14];
    const float* W_ca_cr   = (const float*)d_in[15];
    const float* rpb       = (const float*)d_in[16];
    const float* W_proj_sa = (const float*)d_in[17];
    const float* b_proj_sa = (const float*)d_in[18];
    const float* W_proj_ca = (const float*)d_in[19];
    const float* b_proj_ca = (const float*)d_in[20];
    float* out = (float*)d_out;
    float* ws  = (float*)d_ws;

    // ---- f32 combined-weight temps ----
    float* CW0 = ws;             // 192x576
    float* CW1 = CW0 + 110592;
    float* CW2 = CW1 + 110592;   // 192x192
    float* CW3 = CW2 + 36864;
    float* CW4 = CW3 + 36864;    // 192x384
    float* CW5 = CW4 + 73728;
    float* bqkv_ca = CW5 + 73728;   // 576 concat bias
    // float region total: 442944 floats

    {
        SmallmmJobs J;
        J.Wa[0]=W_sa_cr; J.Wb[0]=W_sa_qkv; J.sc[0]=sa_enh; J.out[0]=CW0; J.NCb[0]=576;
        J.Wa[1]=W_sa_ct; J.Wb[1]=W_sa_qkv; J.sc[1]=sa_enh; J.out[1]=CW1; J.NCb[1]=576;
        J.Wa[2]=W_ca_cr; J.Wb[2]=W_ca_q;   J.sc[2]=ca_enh; J.out[2]=CW2; J.NCb[2]=192;
        J.Wa[3]=W_ca_ct; J.Wb[3]=W_ca_q;   J.sc[3]=ca_enh; J.out[3]=CW3; J.NCb[3]=192;
        J.Wa[4]=W_ca_cr; J.Wb[4]=W_ca_kv;  J.sc[4]=ca_enh; J.out[4]=CW4; J.NCb[4]=384;
        J.Wa[5]=W_ca_ct; J.Wb[5]=W_ca_kv;  J.sc[5]=ca_enh; J.out[5]=CW5; J.NCb[5]=384;
        int bs[7] = {0,108,216,252,288,360,432};
        for (int i = 0; i < 7; ++i) J.base[i] = bs[i];
        smallmm_all<<<432, 256, 0, stream>>>(J);
    }
    concat_bias<<<3, 256, 0, stream>>>(b_ca_q, b_ca_kv, bqkv_ca);

    // ---- K-slabbed fp16 weights (CA q+kv concatenated into NC=576) ----
    ushort* wb = (ushort*)(ws + 442944);
    ushort* WsaqH  = wb;                    // [6][576][32]
    ushort* C0H    = WsaqH + 110592;
    ushort* C1H    = C0H + 110592;
    ushort* WcqkvH = C1H + 110592;          // [6][576][32] = [Wq|Wkv]
    ushort* C24H   = WcqkvH + 110592;       // [C2|C4]
    ushort* C35H   = C24H + 110592;         // [C3|C5]
    ushort* WpsH   = C35H + 110592;         // [6][192][32]
    ushort* WpcH   = WpsH + 36864;
    ushort* chunkU = WpcH + 36864;          // = wb + 737280

    {
        WtJobs J;
        const float* Ws[11] = {W_sa_qkv, CW0, CW1,
                               W_ca_q, CW2, CW3,
                               W_ca_kv, CW4, CW5,
                               W_proj_sa, W_proj_ca};
        ushort* Ds[11] = {WsaqH, C0H, C1H,
                          WcqkvH, C24H, C35H,
                          WcqkvH, C24H, C35H,
                          WpsH, WpcH};
        int NCs[11]  = {576,576,576, 192,192,192, 384,384,384, 192,192};
        int dNCs[11] = {576,576,576, 576,576,576, 576,576,576, 192,192};
        int coffs[11]= {0,0,0, 0,0,0, 192,192,192, 0,0};
        int bs[12] = {0,432,864,1296,1440,1584,1728,2016,2304,2592,2736,2880};
        for (int i = 0; i < 11; ++i) {
            J.W[i]=Ws[i]; J.dh[i]=Ds[i]; J.NC[i]=NCs[i];
            J.dNC[i]=dNCs[i]; J.coff[i]=coffs[i];
        }
        for (int i = 0; i < 12; ++i) J.base[i] = bs[i];
        conv_wT_all<<<2880, 256, 0, stream>>>(J);
    }

    // ---- chunking: 188160 bytes per batch element, 64KB tail pad.
    //      Cap at 1024 so per-chunk intermediates (~192MB) fit the 256MB L3. ----
    long long avail = (long long)ws_size - 442944LL * 4 - 737280LL * 2 - 65536;
    int cbmax = (int)(avail / 188160);
    if (cbmax > 1024) cbmax = 1024;
    if (cbmax < 1) cbmax = 1;

    const long long OUT1 = 2LL * 2048 * 49 * 192;
    dim3 blk(256);

    for (int c0 = 0; c0 < 2048; c0 += cbmax) {
        int cb = (c0 + cbmax <= 2048) ? cbmax : (2048 - c0);
        int M = cb * 49;
        long long SS = (long long)M * 32;
        int gy = (M + 63) / 64;
        int cblk = (int)(((long long)M * 48 + 255) / 256);
        if (cblk > 4096) cblk = 4096;

        // 1-D grids for the swizzled GEMM: nwg = GX * gy * 2
        dim3 g1(6 * gy), g2(2 * gy);

        // =========================== SA branch ===========================
        ushort* XtH = chunkU;                              // [6][M][32]
        ushort* XrH = XtH + (long long)cbmax * 9408;
        ushort* QtH = XrH + (long long)cbmax * 9408;       // [18][M][32]
        ushort* QrH = QtH + (long long)cbmax * 28224;
        ushort* OtH = QrH + (long long)cbmax * 28224;      // [6][M][32]
        ushort* OrH = OtH + (long long)cbmax * 9408;

        conv_x2<<<cblk, blk, 0, stream>>>(
            x_sa + (long long)c0 * 9408, x_sa + (2048LL + c0) * 9408, 9408,
            XtH, XrH, M);

        gemm_f16<576, true, false><<<g1, blk, 0, stream>>>(
            XtH, XrH, C0H, QtH, nullptr,
            XrH, XtH, C1H, QrH, nullptr,
            WsaqH, b_sa_qkv, 0, M);

        attn_f16<<<cb * 6, blk, 0, stream>>>(
            QtH, QtH + 6 * SS, QtH + 12 * SS,
            QrH, QrH + 6 * SS, QrH + 12 * SS,
            SS, rpb, lam_sa, OtH, OrH);

        gemm_f16<192, false, true><<<g2, blk, 0, stream>>>(
            OtH, nullptr, nullptr, nullptr, out + (long long)c0 * 9408,
            OrH, nullptr, nullptr, nullptr, out + (2048LL + c0) * 9408,
            WpsH, b_proj_sa, 9408, M);

        // =========================== CA branch ===========================
        ushort* CXtH = chunkU;                             // [6][M][32]
        ushort* CXrH = CXtH + (long long)cbmax * 9408;
        ushort* CQtH = CXrH + (long long)cbmax * 9408;     // [18][M][32] qkv
        ushort* CQrH = CQtH + (long long)cbmax * 28224;
        ushort* COtH = CQrH + (long long)cbmax * 28224;    // [6][M][32]
        ushort* COrH = COtH + (long long)cbmax * 9408;

        conv_x2<<<cblk, blk, 0, stream>>>(
            x_ca + (long long)c0 * 18816, x_ca + (long long)c0 * 18816 + 9408, 18816,
            CXtH, CXrH, M);

        // qkv_t = xt@[Wq|Wkv] + xr@[C2|C4] ; qkv_r = xr@[Wq|Wkv] + xt@[C3|C5]
        gemm_f16<576, true, false><<<g1, blk, 0, stream>>>(
            CXtH, CXrH, C24H, CQtH, nullptr,
            CXrH, CXtH, C35H, CQrH, nullptr,
            WcqkvH, bqkv_ca, 0, M);

        attn_f16<<<cb * 6, blk, 0, stream>>>(
            CQtH, CQtH + 6 * SS, CQtH + 12 * SS,
            CQrH, CQrH + 6 * SS, CQrH + 12 * SS,
            SS, rpb, lam_ca, COtH, COrH);

        gemm_f16<192, false, true><<<g2, blk, 0, stream>>>(
            COtH, nullptr, nullptr, nullptr, out + OUT1 + (long long)c0 * 18816,
            COrH, nullptr, nullptr, nullptr, out + OUT1 + (long long)c0 * 18816 + 9408,
            WpcH, b_proj_ca, 18816, M);
    }
}